// Round 6
// baseline (665.311 us; speedup 1.0000x reference)
//
#include <hip/hip_runtime.h>
#include <hip/hip_bf16.h>
#include <math.h>

#define D 2048
#define M_ROWS 50000
#define B_ROWS 16384
#define TOPK 5
#define EPSN 1e-12f

typedef __attribute__((ext_vector_type(4))) float f32x4;
typedef __attribute__((ext_vector_type(8))) short s16x8;
typedef __attribute__((ext_vector_type(4))) unsigned short u16x4;

__device__ __forceinline__ unsigned short f2bf(float f) {
  union { float f; unsigned int u; } x; x.f = f;
  unsigned int u = x.u;
  unsigned int r = u + 0x7fffu + ((u >> 16) & 1u);
  return (unsigned short)(r >> 16);
}

__device__ __forceinline__ void gload16(const void* g, void* l) {
  __builtin_amdgcn_global_load_lds(
      (const __attribute__((address_space(1))) unsigned int*)g,
      (__attribute__((address_space(3))) unsigned int*)l, 16, 0, 0);
}

// Subtiled bf16 layout for A_sw/B_sw (GEMM operands), per 16-row x 64-K block:
//   elem_addr(row,k) = ((row>>4)*32 + (k>>6))*1024 + ((k>>5)&1)*512 + ((k>>3)&3)*128 + (row&15)*8 + (k&7)
// This makes every GEMM ds_read_b128 wave-access 1024 contiguous bytes (0 conflicts)
// and every staged K-half 16 wave-uniform 1KB segments (global_load_lds-compatible).
__device__ __forceinline__ size_t sub_addr(int row, int k) {
  return ((size_t)(row >> 4) * 32 + (size_t)(k >> 6)) * 1024
       + (size_t)(((k >> 5) & 1) * 512 + ((k >> 3) & 3) * 128 + (row & 15) * 8);
}

// ---------------- K0: q_norm ----------------
__global__ void k_qnorm(const float* __restrict__ ce, float* __restrict__ qn) {
  __shared__ float red[256];
  int tid = threadIdx.x;
  float s = 0.f;
  for (int t = tid; t < D; t += 256) { float x = ce[t]; s += x * x; }
  red[tid] = s; __syncthreads();
  for (int w = 128; w > 0; w >>= 1) { if (tid < w) red[tid] += red[tid + w]; __syncthreads(); }
  float inv = 1.0f / fmaxf(sqrtf(red[0]), EPSN);
  for (int t = tid; t < D; t += 256) qn[t] = ce[t] * inv;
}

// ---------------- K1: sims over memory bank ----------------
__global__ void k_sims(const float* __restrict__ bank, const float* __restrict__ qn,
                       float* __restrict__ sims) {
  __shared__ float qs[D];
  int tid = threadIdx.x;
  for (int t = tid; t < D; t += 256) qs[t] = qn[t];
  __syncthreads();
  int lane = tid & 63, wid = tid >> 6;
  int gw = (blockIdx.x << 2) + wid;
  int nw = gridDim.x << 2;
  for (int m = gw; m < M_ROWS; m += nw) {
    const float* row = bank + (size_t)m * D;
    float dot = 0.f, sq = 0.f;
#pragma unroll
    for (int i = 0; i < 8; ++i) {
      int off = i * 256 + lane * 4;
      f32x4 a = *(const f32x4*)(row + off);
      f32x4 q = *(const f32x4*)(qs + off);
      dot += a[0]*q[0] + a[1]*q[1] + a[2]*q[2] + a[3]*q[3];
      sq  += a[0]*a[0] + a[1]*a[1] + a[2]*a[2] + a[3]*a[3];
    }
    for (int off = 32; off; off >>= 1) {
      dot += __shfl_xor(dot, off, 64);
      sq  += __shfl_xor(sq,  off, 64);
    }
    if (lane == 0) sims[m] = dot / fmaxf(sqrtf(sq), EPSN);
  }
}

// ---------------- K2: top-5 ----------------
__global__ void k_topk(const float* __restrict__ sims, float* __restrict__ top_sims,
                       int* __restrict__ top_idx) {
  __shared__ float sval[256 * TOPK];
  __shared__ int   sidx[256 * TOPK];
  __shared__ float sv2[64 * TOPK];
  __shared__ int   si2[64 * TOPK];
  int tid = threadIdx.x;
  float lv[TOPK]; int li[TOPK];
#pragma unroll
  for (int j = 0; j < TOPK; ++j) { lv[j] = -INFINITY; li[j] = 0x7fffffff; }
  for (int m = tid; m < M_ROWS; m += 256) {
    float v = sims[m];
    if (v > lv[TOPK-1] || (v == lv[TOPK-1] && m < li[TOPK-1])) {
      lv[TOPK-1] = v; li[TOPK-1] = m;
#pragma unroll
      for (int j = TOPK-1; j > 0; --j) {
        bool sw = (lv[j] > lv[j-1]) || (lv[j] == lv[j-1] && li[j] < li[j-1]);
        if (sw) { float tv=lv[j]; lv[j]=lv[j-1]; lv[j-1]=tv; int ti=li[j]; li[j]=li[j-1]; li[j-1]=ti; }
      }
    }
  }
#pragma unroll
  for (int j = 0; j < TOPK; ++j) { sval[tid*TOPK+j] = lv[j]; sidx[tid*TOPK+j] = li[j]; }
  __syncthreads();
  if (tid < 64) {
    float bv[TOPK]; int bi[TOPK];
    for (int j = 0; j < TOPK; ++j) { bv[j] = -INFINITY; bi[j] = 0x7fffffff; }
    for (int c = tid * 20; c < tid * 20 + 20; ++c) {
      float v = sval[c]; int i = sidx[c];
      if (v > bv[TOPK-1] || (v == bv[TOPK-1] && i < bi[TOPK-1])) {
        bv[TOPK-1] = v; bi[TOPK-1] = i;
        for (int j = TOPK-1; j > 0; --j) {
          bool sw = (bv[j] > bv[j-1]) || (bv[j] == bv[j-1] && bi[j] < bi[j-1]);
          if (sw) { float tv=bv[j]; bv[j]=bv[j-1]; bv[j-1]=tv; int ti=bi[j]; bi[j]=bi[j-1]; bi[j-1]=ti; }
        }
      }
    }
    for (int j = 0; j < TOPK; ++j) { sv2[tid*TOPK+j] = bv[j]; si2[tid*TOPK+j] = bi[j]; }
  }
  __syncthreads();
  if (tid == 0) {
    float bvv[TOPK]; int bii[TOPK];
    for (int j = 0; j < TOPK; ++j) { bvv[j] = -INFINITY; bii[j] = 0x7fffffff; }
    for (int c = 0; c < 64 * TOPK; ++c) {
      float v = sv2[c]; int i = si2[c];
      if (v > bvv[TOPK-1] || (v == bvv[TOPK-1] && i < bii[TOPK-1])) {
        bvv[TOPK-1] = v; bii[TOPK-1] = i;
        for (int j = TOPK-1; j > 0; --j) {
          bool sw = (bvv[j] > bvv[j-1]) || (bvv[j] == bvv[j-1] && bii[j] < bii[j-1]);
          if (sw) { float tv=bvv[j]; bvv[j]=bvv[j-1]; bvv[j-1]=tv; int ti=bii[j]; bii[j]=bii[j-1]; bii[j-1]=ti; }
        }
      }
    }
    for (int j = 0; j < TOPK; ++j) { top_sims[j] = bvv[j]; top_idx[j] = bii[j]; }
  }
}

// ---------------- K3: k,v = memories @ Wk/Wv^T + b ----------------
__global__ void k_kv(const float* __restrict__ mvals, const int* __restrict__ top_idx,
                     const float* __restrict__ Wk, const float* __restrict__ bk,
                     const float* __restrict__ Wv, const float* __restrict__ bvp,
                     float* __restrict__ kb, float* __restrict__ vb) {
  __shared__ float mem[TOPK][D];
  int tid = threadIdx.x;
  for (int j = 0; j < TOPK; ++j) {
    const float* src = mvals + (size_t)top_idx[j] * D;
    for (int t = tid; t < D; t += 256) mem[j][t] = src[t];
  }
  __syncthreads();
  int lane = tid & 63, wid = tid >> 6;
  int c = blockIdx.x * 4 + wid;
  const float* wkr = Wk + (size_t)c * D;
  const float* wvr = Wv + (size_t)c * D;
  float ak[TOPK] = {0,0,0,0,0}, av[TOPK] = {0,0,0,0,0};
#pragma unroll 2
  for (int i = 0; i < 8; ++i) {
    int off = i * 256 + lane * 4;
    f32x4 wk4 = *(const f32x4*)(wkr + off);
    f32x4 wv4 = *(const f32x4*)(wvr + off);
#pragma unroll
    for (int j = 0; j < TOPK; ++j) {
      f32x4 mv = *(const f32x4*)(&mem[j][off]);
      ak[j] += mv[0]*wk4[0] + mv[1]*wk4[1] + mv[2]*wk4[2] + mv[3]*wk4[3];
      av[j] += mv[0]*wv4[0] + mv[1]*wv4[1] + mv[2]*wv4[2] + mv[3]*wv4[3];
    }
  }
  for (int off = 32; off; off >>= 1) {
#pragma unroll
    for (int j = 0; j < TOPK; ++j) {
      ak[j] += __shfl_xor(ak[j], off, 64);
      av[j] += __shfl_xor(av[j], off, 64);
    }
  }
  if (lane == 0) {
#pragma unroll
    for (int j = 0; j < TOPK; ++j) { kb[j*D + c] = ak[j] + bk[c]; vb[j*D + c] = av[j] + bvp[c]; }
  }
}

// ---------------- K4: prep — KQ partials, VW, sbias, WgA bf16 cast (subtiled) ----------------
// grid: [0,256) KQ partials, [256,768) VW, 768 sbias, [769,1281) castB (fast path only)
__global__ void k_prep(const float* __restrict__ Wq, const float* __restrict__ bq,
                       const float* __restrict__ Wg,
                       const float* __restrict__ kb, const float* __restrict__ vb,
                       float* __restrict__ KQpart, float* __restrict__ VW,
                       float* __restrict__ sbias, unsigned short* __restrict__ B_sw) {
  __shared__ float sh[TOPK * D];
  int tid = threadIdx.x;
  int bid = blockIdx.x;
  if (bid < 256) {
    int cc = bid >> 3, tc = bid & 7;
    for (int x = tid; x < TOPK * 64; x += 256) sh[x] = kb[(x >> 6) * D + cc * 64 + (x & 63)];
    __syncthreads();
    float acc[TOPK] = {0,0,0,0,0};
    const float* wq = Wq + (size_t)(cc * 64) * D + tc * 256 + tid;
#pragma unroll 4
    for (int c = 0; c < 64; ++c) {
      float w = wq[(size_t)c * D];
#pragma unroll
      for (int j = 0; j < TOPK; ++j) acc[j] += sh[j * 64 + c] * w;
    }
#pragma unroll
    for (int j = 0; j < TOPK; ++j)
      KQpart[(size_t)(cc * TOPK + j) * D + tc * 256 + tid] = acc[j];
  } else if (bid < 768) {
    for (int x = tid; x < TOPK * D; x += 256) sh[x] = vb[x];
    __syncthreads();
    int lane = tid & 63, wid = tid >> 6;
    int c = (bid - 256) * 4 + wid;
    const float* wg = Wg + (size_t)c * (2 * D) + D;
    float acc[TOPK] = {0,0,0,0,0};
#pragma unroll 2
    for (int i = 0; i < 8; ++i) {
      int off = i * 256 + lane * 4;
      f32x4 g4 = *(const f32x4*)(wg + off);
#pragma unroll
      for (int j = 0; j < TOPK; ++j) {
        f32x4 vv = *(const f32x4*)(&sh[j*D + off]);
        acc[j] += vv[0]*g4[0] + vv[1]*g4[1] + vv[2]*g4[2] + vv[3]*g4[3];
      }
    }
    for (int off = 32; off; off >>= 1)
#pragma unroll
      for (int j = 0; j < TOPK; ++j) acc[j] += __shfl_xor(acc[j], off, 64);
    if (lane == 0)
      for (int j = 0; j < TOPK; ++j) VW[j*D + c] = acc[j];
  } else if (bid == 768) {
    for (int j = 0; j < TOPK; ++j) {
      float s = 0.f;
      for (int t = tid; t < D; t += 256) s += bq[t] * kb[j*D + t];
      sh[tid] = s; __syncthreads();
      for (int w = 128; w > 0; w >>= 1) { if (tid < w) sh[tid] += sh[tid + w]; __syncthreads(); }
      if (tid == 0) sbias[j] = sh[0];
      __syncthreads();
    }
  } else {
    // castB: Wg rows 0..2047, cols 0..2047 (WgA half) -> B_sw in subtiled order
    int base = (bid - 769) * 1024;
#pragma unroll
    for (int it = 0; it < 4; ++it) {
      int id2 = base + it * 256 + tid;      // 0..524287
      int r = id2 >> 8;
      int k = (id2 & 255) * 8;
      const float* src = Wg + (size_t)r * (2 * D) + k;
      f32x4 a = *(const f32x4*)(src);
      f32x4 b = *(const f32x4*)(src + 4);
      s16x8 p;
      p[0]=(short)f2bf(a[0]); p[1]=(short)f2bf(a[1]); p[2]=(short)f2bf(a[2]); p[3]=(short)f2bf(a[3]);
      p[4]=(short)f2bf(b[0]); p[5]=(short)f2bf(b[1]); p[6]=(short)f2bf(b[2]); p[7]=(short)f2bf(b[3]);
      *(s16x8*)(B_sw + sub_addr(r, k)) = p;
    }
  }
}

// ---------------- K4b: reduce 32 KQ partials -> KQ ----------------
__global__ void k_red(const float* __restrict__ KQpart, float* __restrict__ KQ) {
  int x = blockIdx.x * 256 + threadIdx.x;  // 40 blocks -> 10240
  float s = 0.f;
#pragma unroll 8
  for (int cc = 0; cc < 32; ++cc) s += KQpart[(size_t)cc * (TOPK * D) + x];
  KQ[x] = s;
}

// ---------------- K5: scores + softmax -> attn[B][5]; fused no->bf16 subtiled cast ----------------
template <bool WRITE_CAST>
__global__ void k_attn(const float* __restrict__ no, const float* __restrict__ KQ,
                       const float* __restrict__ sbias, const float* __restrict__ top_sims,
                       float* __restrict__ attn, unsigned short* __restrict__ A_sw) {
  __shared__ float kq[TOPK * D];
  int tid = threadIdx.x;
  for (int x = tid; x < TOPK * D; x += 256) kq[x] = KQ[x];
  __syncthreads();
  int lane = tid & 63, wid = tid >> 6;
  int gw = blockIdx.x * 4 + wid, nw = gridDim.x * 4;
  const float inv = 0.02209708691207961f;  // 1/sqrt(2048)
  for (int b = gw; b < B_ROWS; b += nw) {
    const float* row = no + (size_t)b * D;
    float acc[TOPK] = {0,0,0,0,0};
#pragma unroll
    for (int i = 0; i < 4; ++i) {
      int k = i * 512 + lane * 8;
      f32x4 n4a = *(const f32x4*)(row + k);
      f32x4 n4b = *(const f32x4*)(row + k + 4);
#pragma unroll
      for (int j = 0; j < TOPK; ++j) {
        f32x4 ka = *(const f32x4*)(&kq[j*D + k]);
        f32x4 kb2 = *(const f32x4*)(&kq[j*D + k + 4]);
        acc[j] += n4a[0]*ka[0] + n4a[1]*ka[1] + n4a[2]*ka[2] + n4a[3]*ka[3]
                + n4b[0]*kb2[0] + n4b[1]*kb2[1] + n4b[2]*kb2[2] + n4b[3]*kb2[3];
      }
      if (WRITE_CAST) {
        s16x8 p;
        p[0]=(short)f2bf(n4a[0]); p[1]=(short)f2bf(n4a[1]); p[2]=(short)f2bf(n4a[2]); p[3]=(short)f2bf(n4a[3]);
        p[4]=(short)f2bf(n4b[0]); p[5]=(short)f2bf(n4b[1]); p[6]=(short)f2bf(n4b[2]); p[7]=(short)f2bf(n4b[3]);
        *(s16x8*)(A_sw + sub_addr(b, k)) = p;
      }
    }
    for (int off = 32; off; off >>= 1)
#pragma unroll
      for (int j = 0; j < TOPK; ++j) acc[j] += __shfl_xor(acc[j], off, 64);
    if (lane == 0) {
      float s[TOPK], mx = -INFINITY;
      for (int j = 0; j < TOPK; ++j) { s[j] = (acc[j] + sbias[j]) * inv * top_sims[j]; mx = fmaxf(mx, s[j]); }
      float sum = 0.f;
      for (int j = 0; j < TOPK; ++j) { s[j] = __expf(s[j] - mx); sum += s[j]; }
      float r = 1.0f / sum;
      for (int j = 0; j < TOPK; ++j) attn[(size_t)b*TOPK + j] = s[j] * r;
    }
  }
}

// ---------------- K6 (fast): 256x256 8-phase counted-vmcnt bf16 MFMA GEMM ----------------
// Derived-wait schedule (see analysis): per BK=64 tile, 4 phases (mq0/kk0, mq1/kk0,
// mq0/kk1, mq1/kk1). Staging of tile kt+1 runs one K-half per phase (AK0,BK0,AK1,BK1);
// vmcnt(4) checkpoints at phases 1 and 3 guarantee data 2 phases ahead, never draining
// to 0 in steady state. Raw s_barrier (no vmcnt(0) drain); lgkmcnt(0)+sched_barrier(0)
// before each MFMA cluster (rule #18); setprio around MFMA (T5).
union GemmSmem {
  struct { unsigned short A[2][16384]; unsigned short B[2][16384]; } s;  // 128 KB
  float ep[4096];  // 16 KB epilogue alias (after final barrier)
};

#define STAGE(MAT, kt_, kk_, dn_) do {                                          \
    size_t o0 = (((size_t)(rb##MAT + rh0) * 32 + (size_t)(kt_)) << 10) + ((size_t)(kk_) << 9); \
    size_t o1 = (((size_t)(rb##MAT + rh1) * 32 + (size_t)(kt_)) << 10) + ((size_t)(kk_) << 9); \
    gload16(MAT##_sw + o0 + lane * 8, sm.s.MAT[dn_] + rh0 * 1024 + (kk_) * 512); \
    gload16(MAT##_sw + o1 + lane * 8, sm.s.MAT[dn_] + rh1 * 1024 + (kk_) * 512); \
  } while (0)

__global__ __launch_bounds__(512, 1) void k_gemm_bf(
    const unsigned short* __restrict__ A_sw, const unsigned short* __restrict__ B_sw,
    const float* __restrict__ no, const float* __restrict__ bg,
    const float* __restrict__ attn, const float* __restrict__ vb,
    const float* __restrict__ VW, float* __restrict__ out) {
  __shared__ GemmSmem sm;

  int tid = threadIdx.x;
  int lane = tid & 63, wid = tid >> 6;     // 8 waves
  int fr = lane & 15, fg = lane >> 4;
  int wr = wid >> 2, wc = wid & 3;          // 2 (M) x 4 (N)
  int rh0 = wid * 2, rh1 = wid * 2 + 1;     // staging rowhi segments per wave

  int id = blockIdx.x;                      // 512 blocks
  int nt = id & 7, mt = id >> 3;            // per-XCD B-column (1 MB L2-resident)
  int brow = mt * 256, bcol = nt * 256;
  int rbA = mt * 16, rbB = nt * 16;

  f32x4 acc[8][4];
#pragma unroll
  for (int m = 0; m < 8; ++m)
#pragma unroll
    for (int n = 0; n < 4; ++n) acc[m][n] = (f32x4){0.f, 0.f, 0.f, 0.f};

  // prologue: K0 halves of tile 0 -> drain; K1 halves stay in flight (4 units)
  STAGE(A, 0, 0, 0); STAGE(B, 0, 0, 0);
  asm volatile("s_waitcnt vmcnt(0)" ::: "memory");
  STAGE(A, 0, 1, 0); STAGE(B, 0, 1, 0);
  __builtin_amdgcn_s_barrier();

  s16x8 af[4], bfr[4];
  for (int kt = 0; kt < 32; ++kt) {
    int d = kt & 1, dn = d ^ 1;
    const unsigned short* Ab = sm.s.A[d];
    const unsigned short* Bb = sm.s.B[d];
    const bool st = (kt < 31);
    int rdo = fg * 128 + fr * 8;

    // ---- phase 0: (mq0, kk0) ----
#pragma unroll
    for (int m = 0; m < 4; ++m) af[m]  = *(const s16x8*)(Ab + (wr*8 + m)*1024 + rdo);
#pragma unroll
    for (int n = 0; n < 4; ++n) bfr[n] = *(const s16x8*)(Bb + (wc*4 + n)*1024 + rdo);
    if (st) STAGE(A, kt + 1, 0, dn);
    __builtin_amdgcn_s_barrier();
    asm volatile("s_waitcnt lgkmcnt(0)" ::: "memory");
    __builtin_amdgcn_sched_barrier(0);
    __builtin_amdgcn_s_setprio(1);
#pragma unroll
    for (int n = 0; n < 4; ++n)
#pragma unroll
      for (int m = 0; m < 4; ++m)
        acc[m][n] = __builtin_amdgcn_mfma_f32_16x16x32_bf16(af[m], bfr[n], acc[m][n], 0, 0, 0);
    __builtin_amdgcn_s_setprio(0);
    __builtin_amdgcn_s_barrier();

    // ---- phase 1: (mq1, kk0) ----
#pragma unroll
    for (int m = 0; m < 4; ++m) af[m] = *(const s16x8*)(Ab + (wr*8 + 4 + m)*1024 + rdo);
    if (st) STAGE(B, kt + 1, 0, dn);
    __builtin_amdgcn_s_barrier();
    asm volatile("s_waitcnt lgkmcnt(0)" ::: "memory");
    __builtin_amdgcn_sched_barrier(0);
    __builtin_amdgcn_s_setprio(1);
#pragma unroll
    for (int n = 0; n < 4; ++n)
#pragma unroll
      for (int m = 0; m < 4; ++m)
        acc[4 + m][n] = __builtin_amdgcn_mfma_f32_16x16x32_bf16(af[m], bfr[n], acc[4 + m][n], 0, 0, 0);
    __builtin_amdgcn_s_setprio(0);
    if (st) asm volatile("s_waitcnt vmcnt(4)" ::: "memory");   // kt's K1 halves landed
    else    asm volatile("s_waitcnt vmcnt(0)" ::: "memory");   // last tile: full drain
    __builtin_amdgcn_s_barrier();

    // ---- phase 2: (mq0, kk1) ----
#pragma unroll
    for (int m = 0; m < 4; ++m) af[m]  = *(const s16x8*)(Ab + (wr*8 + m)*1024 + 512 + rdo);
#pragma unroll
    for (int n = 0; n < 4; ++n) bfr[n] = *(const s16x8*)(Bb + (wc*4 + n)*1024 + 512 + rdo);
    if (st) STAGE(A, kt + 1, 1, dn);
    __builtin_amdgcn_s_barrier();
    asm volatile("s_waitcnt lgkmcnt(0)" ::: "memory");
    __builtin_amdgcn_sched_barrier(0);
    __builtin_amdgcn_s_setprio(1);
#pragma unroll
    for (int n = 0; n < 4; ++n)
#pragma unroll
      for (int m = 0; m < 4; ++m)
        acc[m][n] = __builtin_amdgcn_mfma_f32_16x16x32_bf16(af[m], bfr[n], acc[m][n], 0, 0, 0);
    __builtin_amdgcn_s_setprio(0);
    __builtin_amdgcn_s_barrier();

    // ---- phase 3: (mq1, kk1) ----
#pragma unroll
    for (int m = 0; m < 4; ++m) af[m] = *(const s16x8*)(Ab + (wr*8 + 4 + m)*1024 + 512 + rdo);
    if (st) STAGE(B, kt + 1, 1, dn);
    __builtin_amdgcn_s_barrier();
    asm volatile("s_waitcnt lgkmcnt(0)" ::: "memory");
    __builtin_amdgcn_sched_barrier(0);
    __builtin_amdgcn_s_setprio(1);
#pragma unroll
    for (int n = 0; n < 4; ++n)
#pragma unroll
      for (int m = 0; m < 4; ++m)
        acc[4 + m][n] = __builtin_amdgcn_mfma_f32_16x16x32_bf16(af[m], bfr[n], acc[4 + m][n], 0, 0, 0);
    __builtin_amdgcn_s_setprio(0);
    if (st) asm volatile("s_waitcnt vmcnt(4)" ::: "memory");   // kt+1's K0 halves landed
    __builtin_amdgcn_s_barrier();
  }

  // epilogue staging (aliases LDS; all counts drained, all waves past final barrier)
  for (int x = tid; x < 1280; x += 512) sm.ep[x] = attn[(size_t)brow * TOPK + x];
  for (int x = tid; x < 1280; x += 512) { int j = x >> 8, c = x & 255; sm.ep[1280 + x] = VW[j*D + bcol + c]; }
  for (int x = tid; x < 1280; x += 512) { int j = x >> 8, c = x & 255; sm.ep[2560 + x] = vb[j*D + bcol + c]; }
  if (tid < 256) sm.ep[3840 + tid] = bg[bcol + tid];
  __syncthreads();

#pragma unroll
  for (int m = 0; m < 8; ++m) {
    int rbase = wr * 128 + m * 16 + fg * 4;
#pragma unroll
    for (int n = 0; n < 4; ++n) {
      int c = wc * 64 + n * 16 + fr;
      float vw0 = sm.ep[1280 + 0*256 + c], vw1 = sm.ep[1280 + 1*256 + c], vw2 = sm.ep[1280 + 2*256 + c],
            vw3 = sm.ep[1280 + 3*256 + c], vw4 = sm.ep[1280 + 4*256 + c];
      float v0 = sm.ep[2560 + 0*256 + c], v1 = sm.ep[2560 + 1*256 + c], v2 = sm.ep[2560 + 2*256 + c],
            v3 = sm.ep[2560 + 3*256 + c], v4 = sm.ep[2560 + 4*256 + c];
      float bgc = sm.ep[3840 + c];
#pragma unroll
      for (int i = 0; i < 4; ++i) {
        int r = rbase + i;
        float a0 = sm.ep[r*5+0], a1 = sm.ep[r*5+1], a2 = sm.ep[r*5+2], a3 = sm.ep[r*5+3], a4 = sm.ep[r*5+4];
        float gl = acc[m][n][i] + bgc + a0*vw0 + a1*vw1 + a2*vw2 + a3*vw3 + a4*vw4;
        float att = a0*v0 + a1*v1 + a2*v2 + a3*v3 + a4*v4;
        float gate = 1.0f / (1.0f + __expf(-gl));
        size_t gi = (size_t)(brow + r) * D + bcol + c;
        out[gi] = no[gi] + gate * att;
      }
    }
  }
}

// ---------------- K6 (fallback): f32-staging GEMM ----------------
#define BM 128
#define BN 128
#define BKf 32
#define LDK (BKf + 8)

__global__ __launch_bounds__(256) void k_gemm_f32(
    const float* __restrict__ no, const float* __restrict__ Wg,
    const float* __restrict__ bg, const float* __restrict__ attn,
    const float* __restrict__ vb, const float* __restrict__ VW,
    float* __restrict__ out) {
  __shared__ unsigned short As[BM * LDK];
  __shared__ unsigned short Bs[BN * LDK];
  __shared__ float ep[2048];

  int tid = threadIdx.x;
  int lane = tid & 63, wid = tid >> 6;
  int brow = blockIdx.x * BM;
  int bcol = blockIdx.y * BN;
  int wr = wid >> 1, wc = wid & 1;

  f32x4 acc[4][4];
#pragma unroll
  for (int m = 0; m < 4; ++m)
#pragma unroll
    for (int n = 0; n < 4; ++n) acc[m][n] = (f32x4){0.f, 0.f, 0.f, 0.f};

  int fr = lane & 15, fg = lane >> 4;

  for (int kt = 0; kt < D / BKf; ++kt) {
    int k0 = kt * BKf;
#pragma unroll
    for (int i = 0; i < 4; ++i) {
      int fid = tid + i * 256;
      int row = fid >> 3, c4 = (fid & 7) * 4;
      f32x4 a4 = *(const f32x4*)(no + (size_t)(brow + row) * D + k0 + c4);
      f32x4 b4 = *(const f32x4*)(Wg + (size_t)(bcol + row) * (2 * D) + k0 + c4);
      u16x4 ab, bb;
      ab[0] = f2bf(a4[0]); ab[1] = f2bf(a4[1]); ab[2] = f2bf(a4[2]); ab[3] = f2bf(a4[3]);
      bb[0] = f2bf(b4[0]); bb[1] = f2bf(b4[1]); bb[2] = f2bf(b4[2]); bb[3] = f2bf(b4[3]);
      *(u16x4*)(&As[row * LDK + c4]) = ab;
      *(u16x4*)(&Bs[row * LDK + c4]) = bb;
    }
    __syncthreads();
    s16x8 af[4], bfr[4];
#pragma unroll
    for (int m = 0; m < 4; ++m) af[m] = *(const s16x8*)(&As[(wr*64 + m*16 + fr) * LDK + fg*8]);
#pragma unroll
    for (int n = 0; n < 4; ++n) bfr[n] = *(const s16x8*)(&Bs[(wc*64 + n*16 + fr) * LDK + fg*8]);
#pragma unroll
    for (int m = 0; m < 4; ++m)
#pragma unroll
      for (int n = 0; n < 4; ++n)
        acc[m][n] = __builtin_amdgcn_mfma_f32_16x16x32_bf16(af[m], bfr[n], acc[m][n], 0, 0, 0);
    __syncthreads();
  }

  for (int x = tid; x < 640; x += 256) ep[x] = attn[(size_t)brow * TOPK + x];
  for (int x = tid; x < 640; x += 256) { int j = x >> 7, c = x & 127; ep[640 + x]  = VW[j*D + bcol + c]; }
  for (int x = tid; x < 640; x += 256) { int j = x >> 7, c = x & 127; ep[1280 + x] = vb[j*D + bcol + c]; }
  if (tid < 128) ep[1920 + tid] = bg[bcol + tid];
  __syncthreads();

#pragma unroll
  for (int m = 0; m < 4; ++m) {
    int rbase = wr * 64 + m * 16 + fg * 4;
#pragma unroll
    for (int n = 0; n < 4; ++n) {
      int c = wc * 64 + n * 16 + fr;
      float vw0 = ep[640 + 0*128 + c], vw1 = ep[640 + 1*128 + c], vw2 = ep[640 + 2*128 + c],
            vw3 = ep[640 + 3*128 + c], vw4 = ep[640 + 4*128 + c];
      float v0 = ep[1280 + 0*128 + c], v1 = ep[1280 + 1*128 + c], v2 = ep[1280 + 2*128 + c],
            v3 = ep[1280 + 3*128 + c], v4 = ep[1280 + 4*128 + c];
      float bgc = ep[1920 + c];
#pragma unroll
      for (int i = 0; i < 4; ++i) {
        int r = rbase + i;
        float a0 = ep[r*5+0], a1 = ep[r*5+1], a2 = ep[r*5+2], a3 = ep[r*5+3], a4 = ep[r*5+4];
        float gl = acc[m][n][i] + bgc + a0*vw0 + a1*vw1 + a2*vw2 + a3*vw3 + a4*vw4;
        float att = a0*v0 + a1*v1 + a2*v2 + a3*v3 + a4*v4;
        float gate = 1.0f / (1.0f + __expf(-gl));
        size_t gi = (size_t)(brow + r) * D + bcol + c;
        out[gi] = no[gi] + gate * att;
      }
    }
  }
}

extern "C" void kernel_launch(void* const* d_in, const int* in_sizes, int n_in,
                              void* d_out, int out_size, void* d_ws, size_t ws_size,
                              hipStream_t stream) {
  (void)in_sizes; (void)n_in; (void)out_size;
  const float* no    = (const float*)d_in[0];
  const float* ce    = (const float*)d_in[1];
  const float* bank  = (const float*)d_in[2];
  const float* mvals = (const float*)d_in[3];
  const float* Wq    = (const float*)d_in[4];
  const float* bq    = (const float*)d_in[5];
  const float* Wk    = (const float*)d_in[6];
  const float* bk    = (const float*)d_in[7];
  const float* Wv    = (const float*)d_in[8];
  const float* bvp   = (const float*)d_in[9];
  const float* Wg    = (const float*)d_in[10];
  const float* bg    = (const float*)d_in[11];
  float* out = (float*)d_out;

  char* ws = (char*)d_ws;
  float* qn       = (float*)(ws + 0);
  float* sims     = (float*)(ws + 16384);
  float* top_sims = (float*)(ws + 220160);
  int*   top_idx  = (int*)  (ws + 220192);
  float* sbias    = (float*)(ws + 220224);
  float* kb       = (float*)(ws + 221184);
  float* vb       = (float*)(ws + 262144);
  float* VW       = (float*)(ws + 303104);
  float* KQpart   = (float*)(ws + 344064);
  float* KQ       = (float*)(ws + 1654784);
  float* attn     = (float*)(ws + 1695744);
  unsigned short* A_sw = (unsigned short*)(ws + 4194304);
  unsigned short* B_sw = (unsigned short*)(ws + 4194304 + (size_t)B_ROWS * D * 2);

  const size_t ws_need = 4194304 + (size_t)B_ROWS * D * 2 + (size_t)D * D * 2;
  const bool fast = ws_size >= ws_need;

  k_qnorm<<<1, 256, 0, stream>>>(ce, qn);
  k_sims<<<1024, 256, 0, stream>>>(bank, qn, sims);
  k_topk<<<1, 256, 0, stream>>>(sims, top_sims, top_idx);
  k_kv<<<512, 256, 0, stream>>>(mvals, top_idx, Wk, bk, Wv, bvp, kb, vb);
  k_prep<<<fast ? 1281 : 769, 256, 0, stream>>>(Wq, bq, Wg, kb, vb, KQpart, VW, sbias, B_sw);
  k_red<<<40, 256, 0, stream>>>(KQpart, KQ);
  if (fast) {
    k_attn<true><<<1024, 256, 0, stream>>>(no, KQ, sbias, top_sims, attn, A_sw);
    k_gemm_bf<<<512, 512, 0, stream>>>(A_sw, B_sw, no, bg, attn, vb, VW, out);
  } else {
    k_attn<false><<<1024, 256, 0, stream>>>(no, KQ, sbias, top_sims, attn, A_sw);
    k_gemm_f32<<<dim3(B_ROWS / BM, D / BN), 256, 0, stream>>>(no, Wg, bg, attn, vb, VW, out);
  }
}

// Round 7
// 608.140 us; speedup vs baseline: 1.0940x; 1.0940x over previous
//
#include <hip/hip_runtime.h>
#include <hip/hip_bf16.h>
#include <math.h>

#define D 2048
#define M_ROWS 50000
#define B_ROWS 16384
#define TOPK 5
#define EPSN 1e-12f

typedef __attribute__((ext_vector_type(4))) float f32x4;
typedef __attribute__((ext_vector_type(8))) short s16x8;
typedef __attribute__((ext_vector_type(4))) unsigned short u16x4;

__device__ __forceinline__ unsigned short f2bf(float f) {
  union { float f; unsigned int u; } x; x.f = f;
  unsigned int u = x.u;
  unsigned int r = u + 0x7fffu + ((u >> 16) & 1u);
  return (unsigned short)(r >> 16);
}

__device__ __forceinline__ void gload16(const void* g, void* l) {
  __builtin_amdgcn_global_load_lds(
      (const __attribute__((address_space(1))) unsigned int*)g,
      (__attribute__((address_space(3))) unsigned int*)l, 16, 0, 0);
}

// Subtiled bf16 layout for A_sw/B_sw, per 16-row x 64-K block (2048 elems):
//   addr(row,k) = ((row>>4)*32 + (k>>6))*1024 + ((k>>5)&1)*512 + ((k>>3)&3)*128 + (row&15)*8 + (k&7)
// Wave-contiguous: lane L <-> (rlow = L&15, kq = L>>4); one 512-elem (1KB) K-half per
// wave write/stage/ds_read — zero bank conflicts, global_load_lds linear-dest compatible.

// ---------------- K0: q_norm ----------------
__global__ void k_qnorm(const float* __restrict__ ce, float* __restrict__ qn) {
  __shared__ float red[256];
  int tid = threadIdx.x;
  float s = 0.f;
  for (int t = tid; t < D; t += 256) { float x = ce[t]; s += x * x; }
  red[tid] = s; __syncthreads();
  for (int w = 128; w > 0; w >>= 1) { if (tid < w) red[tid] += red[tid + w]; __syncthreads(); }
  float inv = 1.0f / fmaxf(sqrtf(red[0]), EPSN);
  for (int t = tid; t < D; t += 256) qn[t] = ce[t] * inv;
}

// ---------------- K1: sims over memory bank ----------------
__global__ void k_sims(const float* __restrict__ bank, const float* __restrict__ qn,
                       float* __restrict__ sims) {
  __shared__ float qs[D];
  int tid = threadIdx.x;
  for (int t = tid; t < D; t += 256) qs[t] = qn[t];
  __syncthreads();
  int lane = tid & 63, wid = tid >> 6;
  int gw = (blockIdx.x << 2) + wid;
  int nw = gridDim.x << 2;
  for (int m = gw; m < M_ROWS; m += nw) {
    const float* row = bank + (size_t)m * D;
    float dot = 0.f, sq = 0.f;
#pragma unroll
    for (int i = 0; i < 8; ++i) {
      int off = i * 256 + lane * 4;
      f32x4 a = *(const f32x4*)(row + off);
      f32x4 q = *(const f32x4*)(qs + off);
      dot += a[0]*q[0] + a[1]*q[1] + a[2]*q[2] + a[3]*q[3];
      sq  += a[0]*a[0] + a[1]*a[1] + a[2]*a[2] + a[3]*a[3];
    }
    for (int off = 32; off; off >>= 1) {
      dot += __shfl_xor(dot, off, 64);
      sq  += __shfl_xor(sq,  off, 64);
    }
    if (lane == 0) sims[m] = dot / fmaxf(sqrtf(sq), EPSN);
  }
}

// ---------------- K2: top-5 ----------------
__global__ void k_topk(const float* __restrict__ sims, float* __restrict__ top_sims,
                       int* __restrict__ top_idx) {
  __shared__ float sval[256 * TOPK];
  __shared__ int   sidx[256 * TOPK];
  __shared__ float sv2[64 * TOPK];
  __shared__ int   si2[64 * TOPK];
  int tid = threadIdx.x;
  float lv[TOPK]; int li[TOPK];
#pragma unroll
  for (int j = 0; j < TOPK; ++j) { lv[j] = -INFINITY; li[j] = 0x7fffffff; }
  for (int m = tid; m < M_ROWS; m += 256) {
    float v = sims[m];
    if (v > lv[TOPK-1] || (v == lv[TOPK-1] && m < li[TOPK-1])) {
      lv[TOPK-1] = v; li[TOPK-1] = m;
#pragma unroll
      for (int j = TOPK-1; j > 0; --j) {
        bool sw = (lv[j] > lv[j-1]) || (lv[j] == lv[j-1] && li[j] < li[j-1]);
        if (sw) { float tv=lv[j]; lv[j]=lv[j-1]; lv[j-1]=tv; int ti=li[j]; li[j]=li[j-1]; li[j-1]=ti; }
      }
    }
  }
#pragma unroll
  for (int j = 0; j < TOPK; ++j) { sval[tid*TOPK+j] = lv[j]; sidx[tid*TOPK+j] = li[j]; }
  __syncthreads();
  if (tid < 64) {
    float bv[TOPK]; int bi[TOPK];
    for (int j = 0; j < TOPK; ++j) { bv[j] = -INFINITY; bi[j] = 0x7fffffff; }
    for (int c = tid * 20; c < tid * 20 + 20; ++c) {
      float v = sval[c]; int i = sidx[c];
      if (v > bv[TOPK-1] || (v == bv[TOPK-1] && i < bi[TOPK-1])) {
        bv[TOPK-1] = v; bi[TOPK-1] = i;
        for (int j = TOPK-1; j > 0; --j) {
          bool sw = (bv[j] > bv[j-1]) || (bv[j] == bv[j-1] && bi[j] < bi[j-1]);
          if (sw) { float tv=bv[j]; bv[j]=bv[j-1]; bv[j-1]=tv; int ti=bi[j]; bi[j]=bi[j-1]; bi[j-1]=ti; }
        }
      }
    }
    for (int j = 0; j < TOPK; ++j) { sv2[tid*TOPK+j] = bv[j]; si2[tid*TOPK+j] = bi[j]; }
  }
  __syncthreads();
  if (tid == 0) {
    float bvv[TOPK]; int bii[TOPK];
    for (int j = 0; j < TOPK; ++j) { bvv[j] = -INFINITY; bii[j] = 0x7fffffff; }
    for (int c = 0; c < 64 * TOPK; ++c) {
      float v = sv2[c]; int i = si2[c];
      if (v > bvv[TOPK-1] || (v == bvv[TOPK-1] && i < bii[TOPK-1])) {
        bvv[TOPK-1] = v; bii[TOPK-1] = i;
        for (int j = TOPK-1; j > 0; --j) {
          bool sw = (bvv[j] > bvv[j-1]) || (bvv[j] == bvv[j-1] && bii[j] < bii[j-1]);
          if (sw) { float tv=bvv[j]; bvv[j]=bvv[j-1]; bvv[j-1]=tv; int ti=bii[j]; bii[j]=bii[j-1]; bii[j-1]=ti; }
        }
      }
    }
    for (int j = 0; j < TOPK; ++j) { top_sims[j] = bvv[j]; top_idx[j] = bii[j]; }
  }
}

// ---------------- K3: k,v = memories @ Wk/Wv^T + b ----------------
__global__ void k_kv(const float* __restrict__ mvals, const int* __restrict__ top_idx,
                     const float* __restrict__ Wk, const float* __restrict__ bk,
                     const float* __restrict__ Wv, const float* __restrict__ bvp,
                     float* __restrict__ kb, float* __restrict__ vb) {
  __shared__ float mem[TOPK][D];
  int tid = threadIdx.x;
  for (int j = 0; j < TOPK; ++j) {
    const float* src = mvals + (size_t)top_idx[j] * D;
    for (int t = tid; t < D; t += 256) mem[j][t] = src[t];
  }
  __syncthreads();
  int lane = tid & 63, wid = tid >> 6;
  int c = blockIdx.x * 4 + wid;
  const float* wkr = Wk + (size_t)c * D;
  const float* wvr = Wv + (size_t)c * D;
  float ak[TOPK] = {0,0,0,0,0}, av[TOPK] = {0,0,0,0,0};
#pragma unroll 2
  for (int i = 0; i < 8; ++i) {
    int off = i * 256 + lane * 4;
    f32x4 wk4 = *(const f32x4*)(wkr + off);
    f32x4 wv4 = *(const f32x4*)(wvr + off);
#pragma unroll
    for (int j = 0; j < TOPK; ++j) {
      f32x4 mv = *(const f32x4*)(&mem[j][off]);
      ak[j] += mv[0]*wk4[0] + mv[1]*wk4[1] + mv[2]*wk4[2] + mv[3]*wk4[3];
      av[j] += mv[0]*wv4[0] + mv[1]*wv4[1] + mv[2]*wv4[2] + mv[3]*wv4[3];
    }
  }
  for (int off = 32; off; off >>= 1) {
#pragma unroll
    for (int j = 0; j < TOPK; ++j) {
      ak[j] += __shfl_xor(ak[j], off, 64);
      av[j] += __shfl_xor(av[j], off, 64);
    }
  }
  if (lane == 0) {
#pragma unroll
    for (int j = 0; j < TOPK; ++j) { kb[j*D + c] = ak[j] + bk[c]; vb[j*D + c] = av[j] + bvp[c]; }
  }
}

// ---------------- K4: prep — KQ partials, VW, sbias, WgA bf16 cast (wave-coalesced) ----
// grid: [0,256) KQ partials, [256,768) VW, 768 sbias, [769,801) castB (fast path only)
__global__ void k_prep(const float* __restrict__ Wq, const float* __restrict__ bq,
                       const float* __restrict__ Wg,
                       const float* __restrict__ kb, const float* __restrict__ vb,
                       float* __restrict__ KQpart, float* __restrict__ VW,
                       float* __restrict__ sbias, unsigned short* __restrict__ B_sw) {
  __shared__ float sh[TOPK * D];
  int tid = threadIdx.x;
  int bid = blockIdx.x;
  if (bid < 256) {
    int cc = bid >> 3, tc = bid & 7;
    for (int x = tid; x < TOPK * 64; x += 256) sh[x] = kb[(x >> 6) * D + cc * 64 + (x & 63)];
    __syncthreads();
    float acc[TOPK] = {0,0,0,0,0};
    const float* wq = Wq + (size_t)(cc * 64) * D + tc * 256 + tid;
#pragma unroll 4
    for (int c = 0; c < 64; ++c) {
      float w = wq[(size_t)c * D];
#pragma unroll
      for (int j = 0; j < TOPK; ++j) acc[j] += sh[j * 64 + c] * w;
    }
#pragma unroll
    for (int j = 0; j < TOPK; ++j)
      KQpart[(size_t)(cc * TOPK + j) * D + tc * 256 + tid] = acc[j];
  } else if (bid < 768) {
    for (int x = tid; x < TOPK * D; x += 256) sh[x] = vb[x];
    __syncthreads();
    int lane = tid & 63, wid = tid >> 6;
    int c = (bid - 256) * 4 + wid;
    const float* wg = Wg + (size_t)c * (2 * D) + D;
    float acc[TOPK] = {0,0,0,0,0};
#pragma unroll 2
    for (int i = 0; i < 8; ++i) {
      int off = i * 256 + lane * 4;
      f32x4 g4 = *(const f32x4*)(wg + off);
#pragma unroll
      for (int j = 0; j < TOPK; ++j) {
        f32x4 vv = *(const f32x4*)(&sh[j*D + off]);
        acc[j] += vv[0]*g4[0] + vv[1]*g4[1] + vv[2]*g4[2] + vv[3]*g4[3];
      }
    }
    for (int off = 32; off; off >>= 1)
#pragma unroll
      for (int j = 0; j < TOPK; ++j) acc[j] += __shfl_xor(acc[j], off, 64);
    if (lane == 0)
      for (int j = 0; j < TOPK; ++j) VW[j*D + c] = acc[j];
  } else if (bid == 768) {
    for (int j = 0; j < TOPK; ++j) {
      float s = 0.f;
      for (int t = tid; t < D; t += 256) s += bq[t] * kb[j*D + t];
      sh[tid] = s; __syncthreads();
      for (int w = 128; w > 0; w >>= 1) { if (tid < w) sh[tid] += sh[tid + w]; __syncthreads(); }
      if (tid == 0) sbias[j] = sh[0];
      __syncthreads();
    }
  } else {
    // castB: 32 blocks x 4 waves; each wave handles 16 Wg rows, writes one
    // contiguous 1KB half-block of B_sw per iteration (lane L <-> (L&15, L>>4)).
    int lane = tid & 63, wid = tid >> 6;
    int r0 = ((bid - 769) * 4 + wid) * 16;
    int rl = lane & 15, kg = lane >> 4;
    const float* src = Wg + (size_t)(r0 + rl) * (2 * D);
    size_t wbase = ((size_t)(r0 >> 4) * 32) << 10;
#pragma unroll 4
    for (int it = 0; it < 64; ++it) {
      int k = it * 32 + kg * 8;
      f32x4 a = *(const f32x4*)(src + k);
      f32x4 b = *(const f32x4*)(src + k + 4);
      s16x8 p;
      p[0]=(short)f2bf(a[0]); p[1]=(short)f2bf(a[1]); p[2]=(short)f2bf(a[2]); p[3]=(short)f2bf(a[3]);
      p[4]=(short)f2bf(b[0]); p[5]=(short)f2bf(b[1]); p[6]=(short)f2bf(b[2]); p[7]=(short)f2bf(b[3]);
      *(s16x8*)(B_sw + wbase + ((size_t)(it >> 1) << 10) + ((it & 1) << 9) + lane * 8) = p;
    }
  }
}

// ---------------- K4b: reduce 32 KQ partials -> KQ ----------------
__global__ void k_red(const float* __restrict__ KQpart, float* __restrict__ KQ) {
  int x = blockIdx.x * 256 + threadIdx.x;  // 40 blocks -> 10240
  float s = 0.f;
#pragma unroll 8
  for (int cc = 0; cc < 32; ++cc) s += KQpart[(size_t)cc * (TOPK * D) + x];
  KQ[x] = s;
}

// ---------------- K5: scores + softmax + fused no->bf16 subtiled coalesced cast ------
// 256 blocks x 4 waves; each wave owns 16 rows. Lane L <-> (row L&15, k-chunk L>>4):
// reads are 128B-contiguous per row; A_sw writes are one 1KB half-block per iteration;
// dot reduce = 2 shuffles; softmax fully lane-parallel (lane = row).
template <bool WRITE_CAST>
__global__ void k_attn(const float* __restrict__ no, const float* __restrict__ KQ,
                       const float* __restrict__ sbias, const float* __restrict__ top_sims,
                       float* __restrict__ attn, unsigned short* __restrict__ A_sw) {
  __shared__ float kq[TOPK * D];
  int tid = threadIdx.x;
  for (int x = tid; x < TOPK * D; x += 256) kq[x] = KQ[x];
  __syncthreads();
  int lane = tid & 63, wid = tid >> 6;
  int b0 = (blockIdx.x * 4 + wid) * 16;
  int rl = lane & 15, kg = lane >> 4;
  const float* row = no + (size_t)(b0 + rl) * D;
  size_t wbase = ((size_t)(b0 >> 4) * 32) << 10;
  float acc[TOPK] = {0, 0, 0, 0, 0};
#pragma unroll 4
  for (int it = 0; it < 64; ++it) {
    int k = it * 32 + kg * 8;
    f32x4 a = *(const f32x4*)(row + k);
    f32x4 b = *(const f32x4*)(row + k + 4);
#pragma unroll
    for (int j = 0; j < TOPK; ++j) {
      f32x4 ka = *(const f32x4*)(&kq[j * D + k]);
      f32x4 kb2 = *(const f32x4*)(&kq[j * D + k + 4]);
      acc[j] += a[0]*ka[0] + a[1]*ka[1] + a[2]*ka[2] + a[3]*ka[3]
              + b[0]*kb2[0] + b[1]*kb2[1] + b[2]*kb2[2] + b[3]*kb2[3];
    }
    if (WRITE_CAST) {
      s16x8 p;
      p[0]=(short)f2bf(a[0]); p[1]=(short)f2bf(a[1]); p[2]=(short)f2bf(a[2]); p[3]=(short)f2bf(a[3]);
      p[4]=(short)f2bf(b[0]); p[5]=(short)f2bf(b[1]); p[6]=(short)f2bf(b[2]); p[7]=(short)f2bf(b[3]);
      *(s16x8*)(A_sw + wbase + ((size_t)(it >> 1) << 10) + ((it & 1) << 9) + lane * 8) = p;
    }
  }
#pragma unroll
  for (int j = 0; j < TOPK; ++j) {
    acc[j] += __shfl_xor(acc[j], 16, 64);
    acc[j] += __shfl_xor(acc[j], 32, 64);
  }
  if (lane < 16) {
    const float inv = 0.02209708691207961f;  // 1/sqrt(2048)
    float s[TOPK], mx = -INFINITY;
#pragma unroll
    for (int j = 0; j < TOPK; ++j) { s[j] = (acc[j] + sbias[j]) * inv * top_sims[j]; mx = fmaxf(mx, s[j]); }
    float sum = 0.f;
#pragma unroll
    for (int j = 0; j < TOPK; ++j) { s[j] = __expf(s[j] - mx); sum += s[j]; }
    float r = 1.0f / sum;
#pragma unroll
    for (int j = 0; j < TOPK; ++j) attn[(size_t)(b0 + rl) * TOPK + j] = s[j] * r;
  }
}

// ---------------- K6 (fast): 256x256, BK=32 half-tiles, 4-deep counted-vmcnt MFMA GEMM
// 4 circular buffers (16KB A + 16KB B each pair) => stage half h+3 while computing h.
// Per-wave vmcnt(8) once per half: waits own loads for h+1 (each wave stages its own
// rh segments for every half), barrier makes it collective. Lead = 5-6 phases.
union GemmSmem {
  struct { unsigned short A[4][8192]; unsigned short B[4][8192]; } s;  // 128 KB
  float ep[4096];  // 16 KB epilogue alias (after final barrier, all counts drained)
};

#define STAGE_M(SW, RB, LB, h_, b_) do {                                         \
    size_t o0 = (((size_t)((RB) + rh0) * 32 + ((h_) >> 1)) << 10) + (((h_) & 1) << 9); \
    size_t o1 = (((size_t)((RB) + rh1) * 32 + ((h_) >> 1)) << 10) + (((h_) & 1) << 9); \
    gload16((SW) + o0 + lane * 8, (LB)[b_] + rh0 * 512);                         \
    gload16((SW) + o1 + lane * 8, (LB)[b_] + rh1 * 512);                         \
  } while (0)

__global__ __launch_bounds__(512, 1) void k_gemm_bf(
    const unsigned short* __restrict__ A_sw, const unsigned short* __restrict__ B_sw,
    const float* __restrict__ no, const float* __restrict__ bg,
    const float* __restrict__ attn, const float* __restrict__ vb,
    const float* __restrict__ VW, float* __restrict__ out) {
  __shared__ GemmSmem sm;

  int tid = threadIdx.x;
  int lane = tid & 63, wid = tid >> 6;     // 8 waves
  int fr = lane & 15, fg = lane >> 4;
  int wr = wid >> 2, wc = wid & 3;          // 2 (M) x 4 (N)
  int rh0 = wid * 2, rh1 = wid * 2 + 1;     // this wave's staging segments

  int id = blockIdx.x;                      // 512 blocks
  int nt = id & 7, mt = id >> 3;            // per-XCD B-column (1 MB L2-resident)
  int brow = mt * 256, bcol = nt * 256;
  int rbA = mt * 16, rbB = nt * 16;

  f32x4 acc[8][4];
#pragma unroll
  for (int m = 0; m < 8; ++m)
#pragma unroll
    for (int n = 0; n < 4; ++n) acc[m][n] = (f32x4){0.f, 0.f, 0.f, 0.f};

  // prologue: stage halves 0,1,2 (12 loads/wave); wait own h0 (oldest 4) landed
  STAGE_M(A_sw, rbA, sm.s.A, 0, 0); STAGE_M(B_sw, rbB, sm.s.B, 0, 0);
  STAGE_M(A_sw, rbA, sm.s.A, 1, 1); STAGE_M(B_sw, rbB, sm.s.B, 1, 1);
  STAGE_M(A_sw, rbA, sm.s.A, 2, 2); STAGE_M(B_sw, rbB, sm.s.B, 2, 2);
  asm volatile("s_waitcnt vmcnt(8)" ::: "memory");
  __builtin_amdgcn_s_barrier();

  s16x8 af[4], bfr[4];
  int rdo = fg * 128 + fr * 8;
  for (int h = 0; h < 64; ++h) {
    int bh = h & 3;
    const unsigned short* Ab = sm.s.A[bh];
    const unsigned short* Bb = sm.s.B[bh];
    const bool st = (h < 61);

    // ---- phase 0 (rows wr*128 .. +64) ----
#pragma unroll
    for (int m = 0; m < 4; ++m) af[m]  = *(const s16x8*)(Ab + (wr*8 + m) * 512 + rdo);
#pragma unroll
    for (int n = 0; n < 4; ++n) bfr[n] = *(const s16x8*)(Bb + (wc*4 + n) * 512 + rdo);
    if (st) STAGE_M(A_sw, rbA, sm.s.A, h + 3, (h + 3) & 3);
    __builtin_amdgcn_s_barrier();
    asm volatile("s_waitcnt lgkmcnt(0)" ::: "memory");
    __builtin_amdgcn_sched_barrier(0);
    __builtin_amdgcn_s_setprio(1);
#pragma unroll
    for (int n = 0; n < 4; ++n)
#pragma unroll
      for (int m = 0; m < 4; ++m)
        acc[m][n] = __builtin_amdgcn_mfma_f32_16x16x32_bf16(af[m], bfr[n], acc[m][n], 0, 0, 0);
    __builtin_amdgcn_s_setprio(0);
    __builtin_amdgcn_s_barrier();

    // ---- phase 1 (rows wr*128+64 .. +128) ----
#pragma unroll
    for (int m = 0; m < 4; ++m) af[m] = *(const s16x8*)(Ab + (wr*8 + 4 + m) * 512 + rdo);
    if (st) STAGE_M(B_sw, rbB, sm.s.B, h + 3, (h + 3) & 3);
    __builtin_amdgcn_s_barrier();
    asm volatile("s_waitcnt lgkmcnt(0)" ::: "memory");
    __builtin_amdgcn_sched_barrier(0);
    __builtin_amdgcn_s_setprio(1);
#pragma unroll
    for (int n = 0; n < 4; ++n)
#pragma unroll
      for (int m = 0; m < 4; ++m)
        acc[4 + m][n] = __builtin_amdgcn_mfma_f32_16x16x32_bf16(af[m], bfr[n], acc[4 + m][n], 0, 0, 0);
    __builtin_amdgcn_s_setprio(0);
    if (st) asm volatile("s_waitcnt vmcnt(8)" ::: "memory");  // own h+1 loads landed
    else    asm volatile("s_waitcnt vmcnt(0)" ::: "memory");  // tail drain
    __builtin_amdgcn_s_barrier();
  }

  // epilogue staging (aliases LDS; after final barrier, all vmcnt drained)
  for (int x = tid; x < 1280; x += 512) sm.ep[x] = attn[(size_t)brow * TOPK + x];
  for (int x = tid; x < 1280; x += 512) { int j = x >> 8, c = x & 255; sm.ep[1280 + x] = VW[j*D + bcol + c]; }
  for (int x = tid; x < 1280; x += 512) { int j = x >> 8, c = x & 255; sm.ep[2560 + x] = vb[j*D + bcol + c]; }
  if (tid < 256) sm.ep[3840 + tid] = bg[bcol + tid];
  __syncthreads();

#pragma unroll
  for (int m = 0; m < 8; ++m) {
    int rbase = wr * 128 + m * 16 + fg * 4;
#pragma unroll
    for (int n = 0; n < 4; ++n) {
      int c = wc * 64 + n * 16 + fr;
      float vw0 = sm.ep[1280 + 0*256 + c], vw1 = sm.ep[1280 + 1*256 + c], vw2 = sm.ep[1280 + 2*256 + c],
            vw3 = sm.ep[1280 + 3*256 + c], vw4 = sm.ep[1280 + 4*256 + c];
      float v0 = sm.ep[2560 + 0*256 + c], v1 = sm.ep[2560 + 1*256 + c], v2 = sm.ep[2560 + 2*256 + c],
            v3 = sm.ep[2560 + 3*256 + c], v4 = sm.ep[2560 + 4*256 + c];
      float bgc = sm.ep[3840 + c];
#pragma unroll
      for (int i = 0; i < 4; ++i) {
        int r = rbase + i;
        float a0 = sm.ep[r*5+0], a1 = sm.ep[r*5+1], a2 = sm.ep[r*5+2], a3 = sm.ep[r*5+3], a4 = sm.ep[r*5+4];
        float gl = acc[m][n][i] + bgc + a0*vw0 + a1*vw1 + a2*vw2 + a3*vw3 + a4*vw4;
        float att = a0*v0 + a1*v1 + a2*v2 + a3*v3 + a4*v4;
        float gate = 1.0f / (1.0f + __expf(-gl));
        size_t gi = (size_t)(brow + r) * D + bcol + c;
        out[gi] = no[gi] + gate * att;
      }
    }
  }
}

// ---------------- K6 (fallback): f32-staging GEMM ----------------
#define BM 128
#define BN 128
#define BKf 32
#define LDK (BKf + 8)

__global__ __launch_bounds__(256) void k_gemm_f32(
    const float* __restrict__ no, const float* __restrict__ Wg,
    const float* __restrict__ bg, const float* __restrict__ attn,
    const float* __restrict__ vb, const float* __restrict__ VW,
    float* __restrict__ out) {
  __shared__ unsigned short As[BM * LDK];
  __shared__ unsigned short Bs[BN * LDK];
  __shared__ float ep[2048];

  int tid = threadIdx.x;
  int lane = tid & 63, wid = tid >> 6;
  int brow = blockIdx.x * BM;
  int bcol = blockIdx.y * BN;
  int wr = wid >> 1, wc = wid & 1;

  f32x4 acc[4][4];
#pragma unroll
  for (int m = 0; m < 4; ++m)
#pragma unroll
    for (int n = 0; n < 4; ++n) acc[m][n] = (f32x4){0.f, 0.f, 0.f, 0.f};

  int fr = lane & 15, fg = lane >> 4;

  for (int kt = 0; kt < D / BKf; ++kt) {
    int k0 = kt * BKf;
#pragma unroll
    for (int i = 0; i < 4; ++i) {
      int fid = tid + i * 256;
      int row = fid >> 3, c4 = (fid & 7) * 4;
      f32x4 a4 = *(const f32x4*)(no + (size_t)(brow + row) * D + k0 + c4);
      f32x4 b4 = *(const f32x4*)(Wg + (size_t)(bcol + row) * (2 * D) + k0 + c4);
      u16x4 ab, bb;
      ab[0] = f2bf(a4[0]); ab[1] = f2bf(a4[1]); ab[2] = f2bf(a4[2]); ab[3] = f2bf(a4[3]);
      bb[0] = f2bf(b4[0]); bb[1] = f2bf(b4[1]); bb[2] = f2bf(b4[2]); bb[3] = f2bf(b4[3]);
      *(u16x4*)(&As[row * LDK + c4]) = ab;
      *(u16x4*)(&Bs[row * LDK + c4]) = bb;
    }
    __syncthreads();
    s16x8 af[4], bfr[4];
#pragma unroll
    for (int m = 0; m < 4; ++m) af[m] = *(const s16x8*)(&As[(wr*64 + m*16 + fr) * LDK + fg*8]);
#pragma unroll
    for (int n = 0; n < 4; ++n) bfr[n] = *(const s16x8*)(&Bs[(wc*64 + n*16 + fr) * LDK + fg*8]);
#pragma unroll
    for (int m = 0; m < 4; ++m)
#pragma unroll
      for (int n = 0; n < 4; ++n)
        acc[m][n] = __builtin_amdgcn_mfma_f32_16x16x32_bf16(af[m], bfr[n], acc[m][n], 0, 0, 0);
    __syncthreads();
  }

  for (int x = tid; x < 640; x += 256) ep[x] = attn[(size_t)brow * TOPK + x];
  for (int x = tid; x < 640; x += 256) { int j = x >> 7, c = x & 127; ep[640 + x]  = VW[j*D + bcol + c]; }
  for (int x = tid; x < 640; x += 256) { int j = x >> 7, c = x & 127; ep[1280 + x] = vb[j*D + bcol + c]; }
  if (tid < 128) ep[1920 + tid] = bg[bcol + tid];
  __syncthreads();

#pragma unroll
  for (int m = 0; m < 4; ++m) {
    int rbase = wr * 64 + m * 16 + fg * 4;
#pragma unroll
    for (int n = 0; n < 4; ++n) {
      int c = wc * 64 + n * 16 + fr;
      float vw0 = ep[640 + 0*128 + c], vw1 = ep[640 + 1*128 + c], vw2 = ep[640 + 2*128 + c],
            vw3 = ep[640 + 3*128 + c], vw4 = ep[640 + 4*128 + c];
      float v0 = ep[1280 + 0*128 + c], v1 = ep[1280 + 1*128 + c], v2 = ep[1280 + 2*128 + c],
            v3 = ep[1280 + 3*128 + c], v4 = ep[1280 + 4*128 + c];
      float bgc = ep[1920 + c];
#pragma unroll
      for (int i = 0; i < 4; ++i) {
        int r = rbase + i;
        float a0 = ep[r*5+0], a1 = ep[r*5+1], a2 = ep[r*5+2], a3 = ep[r*5+3], a4 = ep[r*5+4];
        float gl = acc[m][n][i] + bgc + a0*vw0 + a1*vw1 + a2*vw2 + a3*vw3 + a4*vw4;
        float att = a0*v0 + a1*v1 + a2*v2 + a3*v3 + a4*v4;
        float gate = 1.0f / (1.0f + __expf(-gl));
        size_t gi = (size_t)(brow + r) * D + bcol + c;
        out[gi] = no[gi] + gate * att;
      }
    }
  }
}

extern "C" void kernel_launch(void* const* d_in, const int* in_sizes, int n_in,
                              void* d_out, int out_size, void* d_ws, size_t ws_size,
                              hipStream_t stream) {
  (void)in_sizes; (void)n_in; (void)out_size;
  const float* no    = (const float*)d_in[0];
  const float* ce    = (const float*)d_in[1];
  const float* bank  = (const float*)d_in[2];
  const float* mvals = (const float*)d_in[3];
  const float* Wq    = (const float*)d_in[4];
  const float* bq    = (const float*)d_in[5];
  const float* Wk    = (const float*)d_in[6];
  const float* bk    = (const float*)d_in[7];
  const float* Wv    = (const float*)d_in[8];
  const float* bvp   = (const float*)d_in[9];
  const float* Wg    = (const float*)d_in[10];
  const float* bg    = (const float*)d_in[11];
  float* out = (float*)d_out;

  char* ws = (char*)d_ws;
  float* qn       = (float*)(ws + 0);
  float* sims     = (float*)(ws + 16384);
  float* top_sims = (float*)(ws + 220160);
  int*   top_idx  = (int*)  (ws + 220192);
  float* sbias    = (float*)(ws + 220224);
  float* kb       = (float*)(ws + 221184);
  float* vb       = (float*)(ws + 262144);
  float* VW       = (float*)(ws + 303104);
  float* KQpart   = (float*)(ws + 344064);
  float* KQ       = (float*)(ws + 1654784);
  float* attn     = (float*)(ws + 1695744);
  unsigned short* A_sw = (unsigned short*)(ws + 4194304);
  unsigned short* B_sw = (unsigned short*)(ws + 4194304 + (size_t)B_ROWS * D * 2);

  const size_t ws_need = 4194304 + (size_t)B_ROWS * D * 2 + (size_t)D * D * 2;
  const bool fast = ws_size >= ws_need;

  k_qnorm<<<1, 256, 0, stream>>>(ce, qn);
  k_sims<<<1024, 256, 0, stream>>>(bank, qn, sims);
  k_topk<<<1, 256, 0, stream>>>(sims, top_sims, top_idx);
  k_kv<<<512, 256, 0, stream>>>(mvals, top_idx, Wk, bk, Wv, bvp, kb, vb);
  k_prep<<<fast ? 801 : 769, 256, 0, stream>>>(Wq, bq, Wg, kb, vb, KQpart, VW, sbias, B_sw);
  k_red<<<40, 256, 0, stream>>>(KQpart, KQ);
  if (fast) {
    k_attn<true><<<256, 256, 0, stream>>>(no, KQ, sbias, top_sims, attn, A_sw);
    k_gemm_bf<<<512, 512, 0, stream>>>(A_sw, B_sw, no, bg, attn, vb, VW, out);
  } else {
    k_attn<false><<<256, 256, 0, stream>>>(no, KQ, sbias, top_sims, attn, A_sw);
    k_gemm_f32<<<dim3(B_ROWS / BM, D / BN), 256, 0, stream>>>(no, Wg, bg, attn, vb, VW, out);
  }
}

// Round 8
// 602.917 us; speedup vs baseline: 1.1035x; 1.0087x over previous
//
#include <hip/hip_runtime.h>
#include <hip/hip_bf16.h>
#include <math.h>

#define D 2048
#define M_ROWS 50000
#define B_ROWS 16384
#define TOPK 5
#define EPSN 1e-12f

typedef __attribute__((ext_vector_type(4))) float f32x4;
typedef __attribute__((ext_vector_type(8))) short s16x8;
typedef __attribute__((ext_vector_type(4))) unsigned short u16x4;

__device__ __forceinline__ unsigned short f2bf(float f) {
  union { float f; unsigned int u; } x; x.f = f;
  unsigned int u = x.u;
  unsigned int r = u + 0x7fffu + ((u >> 16) & 1u);
  return (unsigned short)(r >> 16);
}

__device__ __forceinline__ void gload16(const void* g, void* l) {
  __builtin_amdgcn_global_load_lds(
      (const __attribute__((address_space(1))) unsigned int*)g,
      (__attribute__((address_space(3))) unsigned int*)l, 16, 0, 0);
}

// Subtiled bf16 layout for A_sw/B_sw, per 16-row x 64-K block (2048 elems):
//   addr(row,k) = ((row>>4)*32 + (k>>6))*1024 + ((k>>5)&1)*512 + ((k>>3)&3)*128 + (row&15)*8 + (k&7)
// Wave-contiguous: lane L <-> (rlow = L&15, kq = L>>4); one 512-elem (1KB) K-half per
// wave write/stage/ds_read — zero bank conflicts, global_load_lds linear-dest compatible.

// ---------------- K1: sims over memory bank (qnorm fused per-block) ----------------
__global__ void k_sims(const float* __restrict__ bank, const float* __restrict__ ce,
                       float* __restrict__ sims) {
  __shared__ float qs[D];
  __shared__ float red[256];
  int tid = threadIdx.x;
  float s = 0.f;
  for (int t = tid; t < D; t += 256) { float x = ce[t]; s += x * x; }
  red[tid] = s; __syncthreads();
  for (int w = 128; w > 0; w >>= 1) { if (tid < w) red[tid] += red[tid + w]; __syncthreads(); }
  float qinv = 1.0f / fmaxf(sqrtf(red[0]), EPSN);
  for (int t = tid; t < D; t += 256) qs[t] = ce[t] * qinv;
  __syncthreads();
  int lane = tid & 63, wid = tid >> 6;
  int gw = (blockIdx.x << 2) + wid;
  int nw = gridDim.x << 2;
  for (int m = gw; m < M_ROWS; m += nw) {
    const float* row = bank + (size_t)m * D;
    float dot = 0.f, sq = 0.f;
#pragma unroll
    for (int i = 0; i < 8; ++i) {
      int off = i * 256 + lane * 4;
      f32x4 a = *(const f32x4*)(row + off);
      f32x4 q = *(const f32x4*)(qs + off);
      dot += a[0]*q[0] + a[1]*q[1] + a[2]*q[2] + a[3]*q[3];
      sq  += a[0]*a[0] + a[1]*a[1] + a[2]*a[2] + a[3]*a[3];
    }
    for (int off = 32; off; off >>= 1) {
      dot += __shfl_xor(dot, off, 64);
      sq  += __shfl_xor(sq,  off, 64);
    }
    if (lane == 0) sims[m] = dot / fmaxf(sqrtf(sq), EPSN);
  }
}

// ---------------- K2: top-5 ----------------
__global__ void k_topk(const float* __restrict__ sims, float* __restrict__ top_sims,
                       int* __restrict__ top_idx) {
  __shared__ float sval[256 * TOPK];
  __shared__ int   sidx[256 * TOPK];
  __shared__ float sv2[64 * TOPK];
  __shared__ int   si2[64 * TOPK];
  int tid = threadIdx.x;
  float lv[TOPK]; int li[TOPK];
#pragma unroll
  for (int j = 0; j < TOPK; ++j) { lv[j] = -INFINITY; li[j] = 0x7fffffff; }
  for (int m = tid; m < M_ROWS; m += 256) {
    float v = sims[m];
    if (v > lv[TOPK-1] || (v == lv[TOPK-1] && m < li[TOPK-1])) {
      lv[TOPK-1] = v; li[TOPK-1] = m;
#pragma unroll
      for (int j = TOPK-1; j > 0; --j) {
        bool sw = (lv[j] > lv[j-1]) || (lv[j] == lv[j-1] && li[j] < li[j-1]);
        if (sw) { float tv=lv[j]; lv[j]=lv[j-1]; lv[j-1]=tv; int ti=li[j]; li[j]=li[j-1]; li[j-1]=ti; }
      }
    }
  }
#pragma unroll
  for (int j = 0; j < TOPK; ++j) { sval[tid*TOPK+j] = lv[j]; sidx[tid*TOPK+j] = li[j]; }
  __syncthreads();
  if (tid < 64) {
    float bv[TOPK]; int bi[TOPK];
    for (int j = 0; j < TOPK; ++j) { bv[j] = -INFINITY; bi[j] = 0x7fffffff; }
    for (int c = tid * 20; c < tid * 20 + 20; ++c) {
      float v = sval[c]; int i = sidx[c];
      if (v > bv[TOPK-1] || (v == bv[TOPK-1] && i < bi[TOPK-1])) {
        bv[TOPK-1] = v; bi[TOPK-1] = i;
        for (int j = TOPK-1; j > 0; --j) {
          bool sw = (bv[j] > bv[j-1]) || (bv[j] == bv[j-1] && bi[j] < bi[j-1]);
          if (sw) { float tv=bv[j]; bv[j]=bv[j-1]; bv[j-1]=tv; int ti=bi[j]; bi[j]=bi[j-1]; bi[j-1]=ti; }
        }
      }
    }
    for (int j = 0; j < TOPK; ++j) { sv2[tid*TOPK+j] = bv[j]; si2[tid*TOPK+j] = bi[j]; }
  }
  __syncthreads();
  if (tid == 0) {
    float bvv[TOPK]; int bii[TOPK];
    for (int j = 0; j < TOPK; ++j) { bvv[j] = -INFINITY; bii[j] = 0x7fffffff; }
    for (int c = 0; c < 64 * TOPK; ++c) {
      float v = sv2[c]; int i = si2[c];
      if (v > bvv[TOPK-1] || (v == bvv[TOPK-1] && i < bii[TOPK-1])) {
        bvv[TOPK-1] = v; bii[TOPK-1] = i;
        for (int j = TOPK-1; j > 0; --j) {
          bool sw = (bvv[j] > bvv[j-1]) || (bvv[j] == bvv[j-1] && bii[j] < bii[j-1]);
          if (sw) { float tv=bvv[j]; bvv[j]=bvv[j-1]; bvv[j-1]=tv; int ti=bii[j]; bii[j]=bii[j-1]; bii[j-1]=ti; }
        }
      }
    }
    for (int j = 0; j < TOPK; ++j) { top_sims[j] = bvv[j]; top_idx[j] = bii[j]; }
  }
}

// ---------------- K3: k,v = memories @ Wk/Wv^T + b ----------------
__global__ void k_kv(const float* __restrict__ mvals, const int* __restrict__ top_idx,
                     const float* __restrict__ Wk, const float* __restrict__ bk,
                     const float* __restrict__ Wv, const float* __restrict__ bvp,
                     float* __restrict__ kb, float* __restrict__ vb) {
  __shared__ float mem[TOPK][D];
  int tid = threadIdx.x;
  for (int j = 0; j < TOPK; ++j) {
    const float* src = mvals + (size_t)top_idx[j] * D;
    for (int t = tid; t < D; t += 256) mem[j][t] = src[t];
  }
  __syncthreads();
  int lane = tid & 63, wid = tid >> 6;
  int c = blockIdx.x * 4 + wid;
  const float* wkr = Wk + (size_t)c * D;
  const float* wvr = Wv + (size_t)c * D;
  float ak[TOPK] = {0,0,0,0,0}, av[TOPK] = {0,0,0,0,0};
#pragma unroll 2
  for (int i = 0; i < 8; ++i) {
    int off = i * 256 + lane * 4;
    f32x4 wk4 = *(const f32x4*)(wkr + off);
    f32x4 wv4 = *(const f32x4*)(wvr + off);
#pragma unroll
    for (int j = 0; j < TOPK; ++j) {
      f32x4 mv = *(const f32x4*)(&mem[j][off]);
      ak[j] += mv[0]*wk4[0] + mv[1]*wk4[1] + mv[2]*wk4[2] + mv[3]*wk4[3];
      av[j] += mv[0]*wv4[0] + mv[1]*wv4[1] + mv[2]*wv4[2] + mv[3]*wv4[3];
    }
  }
  for (int off = 32; off; off >>= 1) {
#pragma unroll
    for (int j = 0; j < TOPK; ++j) {
      ak[j] += __shfl_xor(ak[j], off, 64);
      av[j] += __shfl_xor(av[j], off, 64);
    }
  }
  if (lane == 0) {
#pragma unroll
    for (int j = 0; j < TOPK; ++j) { kb[j*D + c] = ak[j] + bk[c]; vb[j*D + c] = av[j] + bvp[c]; }
  }
}

// ---------------- K4: prep — KQ partials, VW, sbias, WgA bf16 cast (wave-coalesced) ----
// grid: [0,256) KQ partials, [256,768) VW, 768 sbias, [769,801) castB (fast path only)
__global__ void k_prep(const float* __restrict__ Wq, const float* __restrict__ bq,
                       const float* __restrict__ Wg,
                       const float* __restrict__ kb, const float* __restrict__ vb,
                       float* __restrict__ KQpart, float* __restrict__ VW,
                       float* __restrict__ sbias, unsigned short* __restrict__ B_sw) {
  __shared__ float sh[TOPK * D];
  int tid = threadIdx.x;
  int bid = blockIdx.x;
  if (bid < 256) {
    int cc = bid >> 3, tc = bid & 7;
    for (int x = tid; x < TOPK * 64; x += 256) sh[x] = kb[(x >> 6) * D + cc * 64 + (x & 63)];
    __syncthreads();
    float acc[TOPK] = {0,0,0,0,0};
    const float* wq = Wq + (size_t)(cc * 64) * D + tc * 256 + tid;
#pragma unroll 4
    for (int c = 0; c < 64; ++c) {
      float w = wq[(size_t)c * D];
#pragma unroll
      for (int j = 0; j < TOPK; ++j) acc[j] += sh[j * 64 + c] * w;
    }
#pragma unroll
    for (int j = 0; j < TOPK; ++j)
      KQpart[(size_t)(cc * TOPK + j) * D + tc * 256 + tid] = acc[j];
  } else if (bid < 768) {
    for (int x = tid; x < TOPK * D; x += 256) sh[x] = vb[x];
    __syncthreads();
    int lane = tid & 63, wid = tid >> 6;
    int c = (bid - 256) * 4 + wid;
    const float* wg = Wg + (size_t)c * (2 * D) + D;
    float acc[TOPK] = {0,0,0,0,0};
#pragma unroll 2
    for (int i = 0; i < 8; ++i) {
      int off = i * 256 + lane * 4;
      f32x4 g4 = *(const f32x4*)(wg + off);
#pragma unroll
      for (int j = 0; j < TOPK; ++j) {
        f32x4 vv = *(const f32x4*)(&sh[j*D + off]);
        acc[j] += vv[0]*g4[0] + vv[1]*g4[1] + vv[2]*g4[2] + vv[3]*g4[3];
      }
    }
    for (int off = 32; off; off >>= 1)
#pragma unroll
      for (int j = 0; j < TOPK; ++j) acc[j] += __shfl_xor(acc[j], off, 64);
    if (lane == 0)
      for (int j = 0; j < TOPK; ++j) VW[j*D + c] = acc[j];
  } else if (bid == 768) {
    for (int j = 0; j < TOPK; ++j) {
      float s = 0.f;
      for (int t = tid; t < D; t += 256) s += bq[t] * kb[j*D + t];
      sh[tid] = s; __syncthreads();
      for (int w = 128; w > 0; w >>= 1) { if (tid < w) sh[tid] += sh[tid + w]; __syncthreads(); }
      if (tid == 0) sbias[j] = sh[0];
      __syncthreads();
    }
  } else {
    // castB: 32 blocks x 4 waves; each wave handles 16 Wg rows, writes one
    // contiguous 1KB half-block of B_sw per iteration (lane L <-> (L&15, L>>4)).
    int lane = tid & 63, wid = tid >> 6;
    int r0 = ((bid - 769) * 4 + wid) * 16;
    int rl = lane & 15, kg = lane >> 4;
    const float* src = Wg + (size_t)(r0 + rl) * (2 * D);
    size_t wbase = ((size_t)(r0 >> 4) * 32) << 10;
#pragma unroll 4
    for (int it = 0; it < 64; ++it) {
      int k = it * 32 + kg * 8;
      f32x4 a = *(const f32x4*)(src + k);
      f32x4 b = *(const f32x4*)(src + k + 4);
      s16x8 p;
      p[0]=(short)f2bf(a[0]); p[1]=(short)f2bf(a[1]); p[2]=(short)f2bf(a[2]); p[3]=(short)f2bf(a[3]);
      p[4]=(short)f2bf(b[0]); p[5]=(short)f2bf(b[1]); p[6]=(short)f2bf(b[2]); p[7]=(short)f2bf(b[3]);
      *(s16x8*)(B_sw + wbase + ((size_t)(it >> 1) << 10) + ((it & 1) << 9) + lane * 8) = p;
    }
  }
}

// ---------------- K4b: reduce 32 KQ partials -> KQ ----------------
__global__ void k_red(const float* __restrict__ KQpart, float* __restrict__ KQ) {
  int x = blockIdx.x * 256 + threadIdx.x;  // 40 blocks -> 10240
  float s = 0.f;
#pragma unroll 8
  for (int cc = 0; cc < 32; ++cc) s += KQpart[(size_t)cc * (TOPK * D) + x];
  KQ[x] = s;
}

// ---------------- K5: scores + softmax + fused no->bf16 subtiled coalesced cast ------
template <bool WRITE_CAST>
__global__ void k_attn(const float* __restrict__ no, const float* __restrict__ KQ,
                       const float* __restrict__ sbias, const float* __restrict__ top_sims,
                       float* __restrict__ attn, unsigned short* __restrict__ A_sw) {
  __shared__ float kq[TOPK * D];
  int tid = threadIdx.x;
  for (int x = tid; x < TOPK * D; x += 256) kq[x] = KQ[x];
  __syncthreads();
  int lane = tid & 63, wid = tid >> 6;
  int b0 = (blockIdx.x * 4 + wid) * 16;
  int rl = lane & 15, kg = lane >> 4;
  const float* row = no + (size_t)(b0 + rl) * D;
  size_t wbase = ((size_t)(b0 >> 4) * 32) << 10;
  float acc[TOPK] = {0, 0, 0, 0, 0};
#pragma unroll 4
  for (int it = 0; it < 64; ++it) {
    int k = it * 32 + kg * 8;
    f32x4 a = *(const f32x4*)(row + k);
    f32x4 b = *(const f32x4*)(row + k + 4);
#pragma unroll
    for (int j = 0; j < TOPK; ++j) {
      f32x4 ka = *(const f32x4*)(&kq[j * D + k]);
      f32x4 kb2 = *(const f32x4*)(&kq[j * D + k + 4]);
      acc[j] += a[0]*ka[0] + a[1]*ka[1] + a[2]*ka[2] + a[3]*ka[3]
              + b[0]*kb2[0] + b[1]*kb2[1] + b[2]*kb2[2] + b[3]*kb2[3];
    }
    if (WRITE_CAST) {
      s16x8 p;
      p[0]=(short)f2bf(a[0]); p[1]=(short)f2bf(a[1]); p[2]=(short)f2bf(a[2]); p[3]=(short)f2bf(a[3]);
      p[4]=(short)f2bf(b[0]); p[5]=(short)f2bf(b[1]); p[6]=(short)f2bf(b[2]); p[7]=(short)f2bf(b[3]);
      *(s16x8*)(A_sw + wbase + ((size_t)(it >> 1) << 10) + ((it & 1) << 9) + lane * 8) = p;
    }
  }
#pragma unroll
  for (int j = 0; j < TOPK; ++j) {
    acc[j] += __shfl_xor(acc[j], 16, 64);
    acc[j] += __shfl_xor(acc[j], 32, 64);
  }
  if (lane < 16) {
    const float inv = 0.02209708691207961f;  // 1/sqrt(2048)
    float s[TOPK], mx = -INFINITY;
#pragma unroll
    for (int j = 0; j < TOPK; ++j) { s[j] = (acc[j] + sbias[j]) * inv * top_sims[j]; mx = fmaxf(mx, s[j]); }
    float sum = 0.f;
#pragma unroll
    for (int j = 0; j < TOPK; ++j) { s[j] = __expf(s[j] - mx); sum += s[j]; }
    float r = 1.0f / sum;
#pragma unroll
    for (int j = 0; j < TOPK; ++j) attn[(size_t)(b0 + rl) * TOPK + j] = s[j] * r;
  }
}

// ---------------- K6 (fast): 256x256, BK=32 halves, 4-deep, ONE phase per half ------
// Barrier-minimized: per half = {12 ds_read + stage A,B(h+3)} -> barrier -> lgkmcnt(0)
// -> 32 MFMA/wave -> counted vmcnt -> barrier.  (2 barriers/half vs round-7's 4.)
// Buffer safety: stage(h+3) overwrites buf (h-1)&3, whose reads completed before the
// previous half's MFMA (lgkmcnt(0)) and whose consumers passed the prev ending barrier.
// Read safety: vmcnt(8) at end of half j forces the 4 loads of half j+1 (issued at
// j-2) to land; barrier makes per-wave guarantees collective. Tail j>=61: vmcnt(0).
union GemmSmem {
  struct { unsigned short A[4][8192]; unsigned short B[4][8192]; } s;  // 128 KB
  float ep[4096];  // 16 KB epilogue alias (after final barrier, all counts drained)
};

#define STAGE_M(SW, RB, LB, h_, b_) do {                                         \
    size_t o0 = (((size_t)((RB) + rh0) * 32 + ((h_) >> 1)) << 10) + (((h_) & 1) << 9); \
    size_t o1 = (((size_t)((RB) + rh1) * 32 + ((h_) >> 1)) << 10) + (((h_) & 1) << 9); \
    gload16((SW) + o0 + lane * 8, (LB)[b_] + rh0 * 512);                         \
    gload16((SW) + o1 + lane * 8, (LB)[b_] + rh1 * 512);                         \
  } while (0)

__global__ __launch_bounds__(512, 1) void k_gemm_bf(
    const unsigned short* __restrict__ A_sw, const unsigned short* __restrict__ B_sw,
    const float* __restrict__ no, const float* __restrict__ bg,
    const float* __restrict__ attn, const float* __restrict__ vb,
    const float* __restrict__ VW, float* __restrict__ out) {
  __shared__ GemmSmem sm;

  int tid = threadIdx.x;
  int lane = tid & 63, wid = tid >> 6;     // 8 waves
  int fr = lane & 15, fg = lane >> 4;
  int wr = wid >> 2, wc = wid & 3;          // 2 (M) x 4 (N)
  int rh0 = wid * 2, rh1 = wid * 2 + 1;     // this wave's staging segments

  int id = blockIdx.x;                      // 512 blocks
  int nt = id & 7, mt = id >> 3;            // per-XCD B-column (1 MB L2-resident)
  int brow = mt * 256, bcol = nt * 256;
  int rbA = mt * 16, rbB = nt * 16;

  f32x4 acc[8][4];
#pragma unroll
  for (int m = 0; m < 8; ++m)
#pragma unroll
    for (int n = 0; n < 4; ++n) acc[m][n] = (f32x4){0.f, 0.f, 0.f, 0.f};

  // prologue: stage halves 0,1,2; wait own h0 (oldest 4) landed
  STAGE_M(A_sw, rbA, sm.s.A, 0, 0); STAGE_M(B_sw, rbB, sm.s.B, 0, 0);
  STAGE_M(A_sw, rbA, sm.s.A, 1, 1); STAGE_M(B_sw, rbB, sm.s.B, 1, 1);
  STAGE_M(A_sw, rbA, sm.s.A, 2, 2); STAGE_M(B_sw, rbB, sm.s.B, 2, 2);
  asm volatile("s_waitcnt vmcnt(8)" ::: "memory");
  __builtin_amdgcn_s_barrier();

  s16x8 af[8], bfr[4];
  int rdo = fg * 128 + fr * 8;
  for (int h = 0; h < 64; ++h) {
    int bh = h & 3;
    const unsigned short* Ab = sm.s.A[bh];
    const unsigned short* Bb = sm.s.B[bh];
    const bool st = (h < 61);

#pragma unroll
    for (int m = 0; m < 8; ++m) af[m]  = *(const s16x8*)(Ab + (wr*8 + m) * 512 + rdo);
#pragma unroll
    for (int n = 0; n < 4; ++n) bfr[n] = *(const s16x8*)(Bb + (wc*4 + n) * 512 + rdo);
    if (st) {
      STAGE_M(A_sw, rbA, sm.s.A, h + 3, (h + 3) & 3);
      STAGE_M(B_sw, rbB, sm.s.B, h + 3, (h + 3) & 3);
    }
    __builtin_amdgcn_s_barrier();
    asm volatile("s_waitcnt lgkmcnt(0)" ::: "memory");
    __builtin_amdgcn_sched_barrier(0);
    __builtin_amdgcn_s_setprio(1);
#pragma unroll
    for (int n = 0; n < 4; ++n)
#pragma unroll
      for (int m = 0; m < 8; ++m)
        acc[m][n] = __builtin_amdgcn_mfma_f32_16x16x32_bf16(af[m], bfr[n], acc[m][n], 0, 0, 0);
    __builtin_amdgcn_s_setprio(0);
    if (st) asm volatile("s_waitcnt vmcnt(8)" ::: "memory");  // half h+1 landed
    else    asm volatile("s_waitcnt vmcnt(0)" ::: "memory");  // tail drain
    __builtin_amdgcn_s_barrier();
  }

  // epilogue staging (aliases LDS; after final barrier, all vmcnt drained)
  for (int x = tid; x < 1280; x += 512) sm.ep[x] = attn[(size_t)brow * TOPK + x];
  for (int x = tid; x < 1280; x += 512) { int j = x >> 8, c = x & 255; sm.ep[1280 + x] = VW[j*D + bcol + c]; }
  for (int x = tid; x < 1280; x += 512) { int j = x >> 8, c = x & 255; sm.ep[2560 + x] = vb[j*D + bcol + c]; }
  if (tid < 256) sm.ep[3840 + tid] = bg[bcol + tid];
  __syncthreads();

#pragma unroll
  for (int m = 0; m < 8; ++m) {
    int rbase = wr * 128 + m * 16 + fg * 4;
#pragma unroll
    for (int n = 0; n < 4; ++n) {
      int c = wc * 64 + n * 16 + fr;
      float vw0 = sm.ep[1280 + 0*256 + c], vw1 = sm.ep[1280 + 1*256 + c], vw2 = sm.ep[1280 + 2*256 + c],
            vw3 = sm.ep[1280 + 3*256 + c], vw4 = sm.ep[1280 + 4*256 + c];
      float v0 = sm.ep[2560 + 0*256 + c], v1 = sm.ep[2560 + 1*256 + c], v2 = sm.ep[2560 + 2*256 + c],
            v3 = sm.ep[2560 + 3*256 + c], v4 = sm.ep[2560 + 4*256 + c];
      float bgc = sm.ep[3840 + c];
#pragma unroll
      for (int i = 0; i < 4; ++i) {
        int r = rbase + i;
        float a0 = sm.ep[r*5+0], a1 = sm.ep[r*5+1], a2 = sm.ep[r*5+2], a3 = sm.ep[r*5+3], a4 = sm.ep[r*5+4];
        float gl = acc[m][n][i] + bgc + a0*vw0 + a1*vw1 + a2*vw2 + a3*vw3 + a4*vw4;
        float att = a0*v0 + a1*v1 + a2*v2 + a3*v3 + a4*v4;
        float gate = 1.0f / (1.0f + __expf(-gl));
        size_t gi = (size_t)(brow + r) * D + bcol + c;
        out[gi] = no[gi] + gate * att;
      }
    }
  }
}

// ---------------- K6 (fallback): f32-staging GEMM ----------------
#define BM 128
#define BN 128
#define BKf 32
#define LDK (BKf + 8)

__global__ __launch_bounds__(256) void k_gemm_f32(
    const float* __restrict__ no, const float* __restrict__ Wg,
    const float* __restrict__ bg, const float* __restrict__ attn,
    const float* __restrict__ vb, const float* __restrict__ VW,
    float* __restrict__ out) {
  __shared__ unsigned short As[BM * LDK];
  __shared__ unsigned short Bs[BN * LDK];
  __shared__ float ep[2048];

  int tid = threadIdx.x;
  int lane = tid & 63, wid = tid >> 6;
  int brow = blockIdx.x * BM;
  int bcol = blockIdx.y * BN;
  int wr = wid >> 1, wc = wid & 1;

  f32x4 acc[4][4];
#pragma unroll
  for (int m = 0; m < 4; ++m)
#pragma unroll
    for (int n = 0; n < 4; ++n) acc[m][n] = (f32x4){0.f, 0.f, 0.f, 0.f};

  int fr = lane & 15, fg = lane >> 4;

  for (int kt = 0; kt < D / BKf; ++kt) {
    int k0 = kt * BKf;
#pragma unroll
    for (int i = 0; i < 4; ++i) {
      int fid = tid + i * 256;
      int row = fid >> 3, c4 = (fid & 7) * 4;
      f32x4 a4 = *(const f32x4*)(no + (size_t)(brow + row) * D + k0 + c4);
      f32x4 b4 = *(const f32x4*)(Wg + (size_t)(bcol + row) * (2 * D) + k0 + c4);
      u16x4 ab, bb;
      ab[0] = f2bf(a4[0]); ab[1] = f2bf(a4[1]); ab[2] = f2bf(a4[2]); ab[3] = f2bf(a4[3]);
      bb[0] = f2bf(b4[0]); bb[1] = f2bf(b4[1]); bb[2] = f2bf(b4[2]); bb[3] = f2bf(b4[3]);
      *(u16x4*)(&As[row * LDK + c4]) = ab;
      *(u16x4*)(&Bs[row * LDK + c4]) = bb;
    }
    __syncthreads();
    s16x8 af[4], bfr[4];
#pragma unroll
    for (int m = 0; m < 4; ++m) af[m] = *(const s16x8*)(&As[(wr*64 + m*16 + fr) * LDK + fg*8]);
#pragma unroll
    for (int n = 0; n < 4; ++n) bfr[n] = *(const s16x8*)(&Bs[(wc*64 + n*16 + fr) * LDK + fg*8]);
#pragma unroll
    for (int m = 0; m < 4; ++m)
#pragma unroll
      for (int n = 0; n < 4; ++n)
        acc[m][n] = __builtin_amdgcn_mfma_f32_16x16x32_bf16(af[m], bfr[n], acc[m][n], 0, 0, 0);
    __syncthreads();
  }

  for (int x = tid; x < 640; x += 256) ep[x] = attn[(size_t)brow * TOPK + x];
  for (int x = tid; x < 640; x += 256) { int j = x >> 7, c = x & 127; ep[640 + x]  = VW[j*D + bcol + c]; }
  for (int x = tid; x < 640; x += 256) { int j = x >> 7, c = x & 127; ep[1280 + x] = vb[j*D + bcol + c]; }
  if (tid < 128) ep[1920 + tid] = bg[bcol + tid];
  __syncthreads();

#pragma unroll
  for (int m = 0; m < 4; ++m) {
    int rbase = wr * 64 + m * 16 + fg * 4;
#pragma unroll
    for (int n = 0; n < 4; ++n) {
      int c = wc * 64 + n * 16 + fr;
      float vw0 = ep[640 + 0*128 + c], vw1 = ep[640 + 1*128 + c], vw2 = ep[640 + 2*128 + c],
            vw3 = ep[640 + 3*128 + c], vw4 = ep[640 + 4*128 + c];
      float v0 = ep[1280 + 0*128 + c], v1 = ep[1280 + 1*128 + c], v2 = ep[1280 + 2*128 + c],
            v3 = ep[1280 + 3*128 + c], v4 = ep[1280 + 4*128 + c];
      float bgc = ep[1920 + c];
#pragma unroll
      for (int i = 0; i < 4; ++i) {
        int r = rbase + i;
        float a0 = ep[r*5+0], a1 = ep[r*5+1], a2 = ep[r*5+2], a3 = ep[r*5+3], a4 = ep[r*5+4];
        float gl = acc[m][n][i] + bgc + a0*vw0 + a1*vw1 + a2*vw2 + a3*vw3 + a4*vw4;
        float att = a0*v0 + a1*v1 + a2*v2 + a3*v3 + a4*v4;
        float gate = 1.0f / (1.0f + __expf(-gl));
        size_t gi = (size_t)(brow + r) * D + bcol + c;
        out[gi] = no[gi] + gate * att;
      }
    }
  }
}

extern "C" void kernel_launch(void* const* d_in, const int* in_sizes, int n_in,
                              void* d_out, int out_size, void* d_ws, size_t ws_size,
                              hipStream_t stream) {
  (void)in_sizes; (void)n_in; (void)out_size;
  const float* no    = (const float*)d_in[0];
  const float* ce    = (const float*)d_in[1];
  const float* bank  = (const float*)d_in[2];
  const float* mvals = (const float*)d_in[3];
  const float* Wq    = (const float*)d_in[4];
  const float* bq    = (const float*)d_in[5];
  const float* Wk    = (const float*)d_in[6];
  const float* bk    = (const float*)d_in[7];
  const float* Wv    = (const float*)d_in[8];
  const float* bvp   = (const float*)d_in[9];
  const float* Wg    = (const float*)d_in[10];
  const float* bg    = (const float*)d_in[11];
  float* out = (float*)d_out;

  char* ws = (char*)d_ws;
  float* sims     = (float*)(ws + 16384);
  float* top_sims = (float*)(ws + 220160);
  int*   top_idx  = (int*)  (ws + 220192);
  float* sbias    = (float*)(ws + 220224);
  float* kb       = (float*)(ws + 221184);
  float* vb       = (float*)(ws + 262144);
  float* VW       = (float*)(ws + 303104);
  float* KQpart   = (float*)(ws + 344064);
  float* KQ       = (float*)(ws + 1654784);
  float* attn     = (float*)(ws + 1695744);
  unsigned short* A_sw = (unsigned short*)(ws + 4194304);
  unsigned short* B_sw = (unsigned short*)(ws + 4194304 + (size_t)B_ROWS * D * 2);

  const size_t ws_need = 4194304 + (size_t)B_ROWS * D * 2 + (size_t)D * D * 2;
  const bool fast = ws_size >= ws_need;

  k_sims<<<1024, 256, 0, stream>>>(bank, ce, sims);
  k_topk<<<1, 256, 0, stream>>>(sims, top_sims, top_idx);
  k_kv<<<512, 256, 0, stream>>>(mvals, top_idx, Wk, bk, Wv, bvp, kb, vb);
  k_prep<<<fast ? 801 : 769, 256, 0, stream>>>(Wq, bq, Wg, kb, vb, KQpart, VW, sbias, B_sw);
  k_red<<<40, 256, 0, stream>>>(KQpart, KQ);
  if (fast) {
    k_attn<true><<<256, 256, 0, stream>>>(no, KQ, sbias, top_sims, attn, A_sw);
    k_gemm_bf<<<512, 512, 0, stream>>>(A_sw, B_sw, no, bg, attn, vb, VW, out);
  } else {
    k_attn<false><<<256, 256, 0, stream>>>(no, KQ, sbias, top_sims, attn, A_sw);
    k_gemm_f32<<<dim3(B_ROWS / BM, D / BN), 256, 0, stream>>>(no, Wg, bg, attn, vb, VW, out);
  }
}

// Round 9
// 590.155 us; speedup vs baseline: 1.1274x; 1.0216x over previous
//
#include <hip/hip_runtime.h>
#include <hip/hip_bf16.h>
#include <math.h>

#define D 2048
#define M_ROWS 50000
#define B_ROWS 16384
#define TOPK 5
#define EPSN 1e-12f

typedef __attribute__((ext_vector_type(4))) float f32x4;
typedef __attribute__((ext_vector_type(8))) short s16x8;
typedef __attribute__((ext_vector_type(4))) unsigned short u16x4;

__device__ __forceinline__ unsigned short f2bf(float f) {
  union { float f; unsigned int u; } x; x.f = f;
  unsigned int u = x.u;
  unsigned int r = u + 0x7fffu + ((u >> 16) & 1u);
  return (unsigned short)(r >> 16);
}

__device__ __forceinline__ void gload16(const void* g, void* l) {
  __builtin_amdgcn_global_load_lds(
      (const __attribute__((address_space(1))) unsigned int*)g,
      (__attribute__((address_space(3))) unsigned int*)l, 16, 0, 0);
}

// Subtiled bf16 layout for A_sw/B_sw, per 16-row x 64-K block (2048 elems):
//   addr(row,k) = ((row>>4)*32 + (k>>6))*1024 + ((k>>5)&1)*512 + ((k>>3)&3)*128 + (row&15)*8 + (k&7)
// Wave-contiguous: lane L <-> (rlow = L&15, kq = L>>4); one 512-elem (1KB) K-half per
// wave write/stage/ds_read — zero bank conflicts, global_load_lds linear-dest compatible.

// ---------------- K1: sims over memory bank (qnorm fused per-block) ----------------
__global__ void k_sims(const float* __restrict__ bank, const float* __restrict__ ce,
                       float* __restrict__ sims) {
  __shared__ float qs[D];
  __shared__ float red[256];
  int tid = threadIdx.x;
  float s = 0.f;
  for (int t = tid; t < D; t += 256) { float x = ce[t]; s += x * x; }
  red[tid] = s; __syncthreads();
  for (int w = 128; w > 0; w >>= 1) { if (tid < w) red[tid] += red[tid + w]; __syncthreads(); }
  float qinv = 1.0f / fmaxf(sqrtf(red[0]), EPSN);
  for (int t = tid; t < D; t += 256) qs[t] = ce[t] * qinv;
  __syncthreads();
  int lane = tid & 63, wid = tid >> 6;
  int gw = (blockIdx.x << 2) + wid;
  int nw = gridDim.x << 2;
  for (int m = gw; m < M_ROWS; m += nw) {
    const float* row = bank + (size_t)m * D;
    float dot = 0.f, sq = 0.f;
#pragma unroll
    for (int i = 0; i < 8; ++i) {
      int off = i * 256 + lane * 4;
      f32x4 a = *(const f32x4*)(row + off);
      f32x4 q = *(const f32x4*)(qs + off);
      dot += a[0]*q[0] + a[1]*q[1] + a[2]*q[2] + a[3]*q[3];
      sq  += a[0]*a[0] + a[1]*a[1] + a[2]*a[2] + a[3]*a[3];
    }
    for (int off = 32; off; off >>= 1) {
      dot += __shfl_xor(dot, off, 64);
      sq  += __shfl_xor(sq,  off, 64);
    }
    if (lane == 0) sims[m] = dot / fmaxf(sqrtf(sq), EPSN);
  }
}

// ---------------- K2: top-5 ----------------
__global__ void k_topk(const float* __restrict__ sims, float* __restrict__ top_sims,
                       int* __restrict__ top_idx) {
  __shared__ float sval[256 * TOPK];
  __shared__ int   sidx[256 * TOPK];
  __shared__ float sv2[64 * TOPK];
  __shared__ int   si2[64 * TOPK];
  int tid = threadIdx.x;
  float lv[TOPK]; int li[TOPK];
#pragma unroll
  for (int j = 0; j < TOPK; ++j) { lv[j] = -INFINITY; li[j] = 0x7fffffff; }
  for (int m = tid; m < M_ROWS; m += 256) {
    float v = sims[m];
    if (v > lv[TOPK-1] || (v == lv[TOPK-1] && m < li[TOPK-1])) {
      lv[TOPK-1] = v; li[TOPK-1] = m;
#pragma unroll
      for (int j = TOPK-1; j > 0; --j) {
        bool sw = (lv[j] > lv[j-1]) || (lv[j] == lv[j-1] && li[j] < li[j-1]);
        if (sw) { float tv=lv[j]; lv[j]=lv[j-1]; lv[j-1]=tv; int ti=li[j]; li[j]=li[j-1]; li[j-1]=ti; }
      }
    }
  }
#pragma unroll
  for (int j = 0; j < TOPK; ++j) { sval[tid*TOPK+j] = lv[j]; sidx[tid*TOPK+j] = li[j]; }
  __syncthreads();
  if (tid < 64) {
    float bv[TOPK]; int bi[TOPK];
    for (int j = 0; j < TOPK; ++j) { bv[j] = -INFINITY; bi[j] = 0x7fffffff; }
    for (int c = tid * 20; c < tid * 20 + 20; ++c) {
      float v = sval[c]; int i = sidx[c];
      if (v > bv[TOPK-1] || (v == bv[TOPK-1] && i < bi[TOPK-1])) {
        bv[TOPK-1] = v; bi[TOPK-1] = i;
        for (int j = TOPK-1; j > 0; --j) {
          bool sw = (bv[j] > bv[j-1]) || (bv[j] == bv[j-1] && bi[j] < bi[j-1]);
          if (sw) { float tv=bv[j]; bv[j]=bv[j-1]; bv[j-1]=tv; int ti=bi[j]; bi[j]=bi[j-1]; bi[j-1]=ti; }
        }
      }
    }
    for (int j = 0; j < TOPK; ++j) { sv2[tid*TOPK+j] = bv[j]; si2[tid*TOPK+j] = bi[j]; }
  }
  __syncthreads();
  if (tid == 0) {
    float bvv[TOPK]; int bii[TOPK];
    for (int j = 0; j < TOPK; ++j) { bvv[j] = -INFINITY; bii[j] = 0x7fffffff; }
    for (int c = 0; c < 64 * TOPK; ++c) {
      float v = sv2[c]; int i = si2[c];
      if (v > bvv[TOPK-1] || (v == bvv[TOPK-1] && i < bii[TOPK-1])) {
        bvv[TOPK-1] = v; bii[TOPK-1] = i;
        for (int j = TOPK-1; j > 0; --j) {
          bool sw = (bvv[j] > bvv[j-1]) || (bvv[j] == bvv[j-1] && bii[j] < bii[j-1]);
          if (sw) { float tv=bvv[j]; bvv[j]=bvv[j-1]; bvv[j-1]=tv; int ti=bii[j]; bii[j]=bii[j-1]; bii[j-1]=ti; }
        }
      }
    }
    for (int j = 0; j < TOPK; ++j) { top_sims[j] = bvv[j]; top_idx[j] = bii[j]; }
  }
}

// ---------------- K3: k,v = memories @ Wk/Wv^T + b ----------------
__global__ void k_kv(const float* __restrict__ mvals, const int* __restrict__ top_idx,
                     const float* __restrict__ Wk, const float* __restrict__ bk,
                     const float* __restrict__ Wv, const float* __restrict__ bvp,
                     float* __restrict__ kb, float* __restrict__ vb) {
  __shared__ float mem[TOPK][D];
  int tid = threadIdx.x;
  for (int j = 0; j < TOPK; ++j) {
    const float* src = mvals + (size_t)top_idx[j] * D;
    for (int t = tid; t < D; t += 256) mem[j][t] = src[t];
  }
  __syncthreads();
  int lane = tid & 63, wid = tid >> 6;
  int c = blockIdx.x * 4 + wid;
  const float* wkr = Wk + (size_t)c * D;
  const float* wvr = Wv + (size_t)c * D;
  float ak[TOPK] = {0,0,0,0,0}, av[TOPK] = {0,0,0,0,0};
#pragma unroll 2
  for (int i = 0; i < 8; ++i) {
    int off = i * 256 + lane * 4;
    f32x4 wk4 = *(const f32x4*)(wkr + off);
    f32x4 wv4 = *(const f32x4*)(wvr + off);
#pragma unroll
    for (int j = 0; j < TOPK; ++j) {
      f32x4 mv = *(const f32x4*)(&mem[j][off]);
      ak[j] += mv[0]*wk4[0] + mv[1]*wk4[1] + mv[2]*wk4[2] + mv[3]*wk4[3];
      av[j] += mv[0]*wv4[0] + mv[1]*wv4[1] + mv[2]*wv4[2] + mv[3]*wv4[3];
    }
  }
  for (int off = 32; off; off >>= 1) {
#pragma unroll
    for (int j = 0; j < TOPK; ++j) {
      ak[j] += __shfl_xor(ak[j], off, 64);
      av[j] += __shfl_xor(av[j], off, 64);
    }
  }
  if (lane == 0) {
#pragma unroll
    for (int j = 0; j < TOPK; ++j) { kb[j*D + c] = ak[j] + bk[c]; vb[j*D + c] = av[j] + bvp[c]; }
  }
}

// ---------------- K4: prep — KQ partials, VW, sbias, WgA bf16 cast (wave-coalesced) ----
// grid: [0,256) KQ partials, [256,768) VW, 768 sbias, [769,801) castB (fast path only)
__global__ void k_prep(const float* __restrict__ Wq, const float* __restrict__ bq,
                       const float* __restrict__ Wg,
                       const float* __restrict__ kb, const float* __restrict__ vb,
                       float* __restrict__ KQpart, float* __restrict__ VW,
                       float* __restrict__ sbias, unsigned short* __restrict__ B_sw) {
  __shared__ float sh[TOPK * D];
  int tid = threadIdx.x;
  int bid = blockIdx.x;
  if (bid < 256) {
    int cc = bid >> 3, tc = bid & 7;
    for (int x = tid; x < TOPK * 64; x += 256) sh[x] = kb[(x >> 6) * D + cc * 64 + (x & 63)];
    __syncthreads();
    float acc[TOPK] = {0,0,0,0,0};
    const float* wq = Wq + (size_t)(cc * 64) * D + tc * 256 + tid;
#pragma unroll 4
    for (int c = 0; c < 64; ++c) {
      float w = wq[(size_t)c * D];
#pragma unroll
      for (int j = 0; j < TOPK; ++j) acc[j] += sh[j * 64 + c] * w;
    }
#pragma unroll
    for (int j = 0; j < TOPK; ++j)
      KQpart[(size_t)(cc * TOPK + j) * D + tc * 256 + tid] = acc[j];
  } else if (bid < 768) {
    for (int x = tid; x < TOPK * D; x += 256) sh[x] = vb[x];
    __syncthreads();
    int lane = tid & 63, wid = tid >> 6;
    int c = (bid - 256) * 4 + wid;
    const float* wg = Wg + (size_t)c * (2 * D) + D;
    float acc[TOPK] = {0,0,0,0,0};
#pragma unroll 2
    for (int i = 0; i < 8; ++i) {
      int off = i * 256 + lane * 4;
      f32x4 g4 = *(const f32x4*)(wg + off);
#pragma unroll
      for (int j = 0; j < TOPK; ++j) {
        f32x4 vv = *(const f32x4*)(&sh[j*D + off]);
        acc[j] += vv[0]*g4[0] + vv[1]*g4[1] + vv[2]*g4[2] + vv[3]*g4[3];
      }
    }
    for (int off = 32; off; off >>= 1)
#pragma unroll
      for (int j = 0; j < TOPK; ++j) acc[j] += __shfl_xor(acc[j], off, 64);
    if (lane == 0)
      for (int j = 0; j < TOPK; ++j) VW[j*D + c] = acc[j];
  } else if (bid == 768) {
    for (int j = 0; j < TOPK; ++j) {
      float s = 0.f;
      for (int t = tid; t < D; t += 256) s += bq[t] * kb[j*D + t];
      sh[tid] = s; __syncthreads();
      for (int w = 128; w > 0; w >>= 1) { if (tid < w) sh[tid] += sh[tid + w]; __syncthreads(); }
      if (tid == 0) sbias[j] = sh[0];
      __syncthreads();
    }
  } else {
    // castB: 32 blocks x 4 waves; each wave handles 16 Wg rows, writes one
    // contiguous 1KB half-block of B_sw per iteration (lane L <-> (L&15, L>>4)).
    int lane = tid & 63, wid = tid >> 6;
    int r0 = ((bid - 769) * 4 + wid) * 16;
    int rl = lane & 15, kg = lane >> 4;
    const float* src = Wg + (size_t)(r0 + rl) * (2 * D);
    size_t wbase = ((size_t)(r0 >> 4) * 32) << 10;
#pragma unroll 4
    for (int it = 0; it < 64; ++it) {
      int k = it * 32 + kg * 8;
      f32x4 a = *(const f32x4*)(src + k);
      f32x4 b = *(const f32x4*)(src + k + 4);
      s16x8 p;
      p[0]=(short)f2bf(a[0]); p[1]=(short)f2bf(a[1]); p[2]=(short)f2bf(a[2]); p[3]=(short)f2bf(a[3]);
      p[4]=(short)f2bf(b[0]); p[5]=(short)f2bf(b[1]); p[6]=(short)f2bf(b[2]); p[7]=(short)f2bf(b[3]);
      *(s16x8*)(B_sw + wbase + ((size_t)(it >> 1) << 10) + ((it & 1) << 9) + lane * 8) = p;
    }
  }
}

// ---------------- K4b: reduce 32 KQ partials -> KQ ----------------
__global__ void k_red(const float* __restrict__ KQpart, float* __restrict__ KQ) {
  int x = blockIdx.x * 256 + threadIdx.x;  // 40 blocks -> 10240
  float s = 0.f;
#pragma unroll 8
  for (int cc = 0; cc < 32; ++cc) s += KQpart[(size_t)cc * (TOPK * D) + x];
  KQ[x] = s;
}

// ---------------- K5: scores + softmax + fused no->bf16 subtiled coalesced cast ------
// Nontemporal `no` reads: `no` streams through once here; keep it from evicting
// A_sw/B_sw (the gemm's hot set) out of L3.
template <bool WRITE_CAST>
__global__ void k_attn(const float* __restrict__ no, const float* __restrict__ KQ,
                       const float* __restrict__ sbias, const float* __restrict__ top_sims,
                       float* __restrict__ attn, unsigned short* __restrict__ A_sw) {
  __shared__ float kq[TOPK * D];
  int tid = threadIdx.x;
  for (int x = tid; x < TOPK * D; x += 256) kq[x] = KQ[x];
  __syncthreads();
  int lane = tid & 63, wid = tid >> 6;
  int b0 = (blockIdx.x * 4 + wid) * 16;
  int rl = lane & 15, kg = lane >> 4;
  const float* row = no + (size_t)(b0 + rl) * D;
  size_t wbase = ((size_t)(b0 >> 4) * 32) << 10;
  float acc[TOPK] = {0, 0, 0, 0, 0};
#pragma unroll 4
  for (int it = 0; it < 64; ++it) {
    int k = it * 32 + kg * 8;
    f32x4 a = __builtin_nontemporal_load((const f32x4*)(row + k));
    f32x4 b = __builtin_nontemporal_load((const f32x4*)(row + k + 4));
#pragma unroll
    for (int j = 0; j < TOPK; ++j) {
      f32x4 ka = *(const f32x4*)(&kq[j * D + k]);
      f32x4 kb2 = *(const f32x4*)(&kq[j * D + k + 4]);
      acc[j] += a[0]*ka[0] + a[1]*ka[1] + a[2]*ka[2] + a[3]*ka[3]
              + b[0]*kb2[0] + b[1]*kb2[1] + b[2]*kb2[2] + b[3]*kb2[3];
    }
    if (WRITE_CAST) {
      s16x8 p;
      p[0]=(short)f2bf(a[0]); p[1]=(short)f2bf(a[1]); p[2]=(short)f2bf(a[2]); p[3]=(short)f2bf(a[3]);
      p[4]=(short)f2bf(b[0]); p[5]=(short)f2bf(b[1]); p[6]=(short)f2bf(b[2]); p[7]=(short)f2bf(b[3]);
      *(s16x8*)(A_sw + wbase + ((size_t)(it >> 1) << 10) + ((it & 1) << 9) + lane * 8) = p;
    }
  }
#pragma unroll
  for (int j = 0; j < TOPK; ++j) {
    acc[j] += __shfl_xor(acc[j], 16, 64);
    acc[j] += __shfl_xor(acc[j], 32, 64);
  }
  if (lane < 16) {
    const float inv = 0.02209708691207961f;  // 1/sqrt(2048)
    float s[TOPK], mx = -INFINITY;
#pragma unroll
    for (int j = 0; j < TOPK; ++j) { s[j] = (acc[j] + sbias[j]) * inv * top_sims[j]; mx = fmaxf(mx, s[j]); }
    float sum = 0.f;
#pragma unroll
    for (int j = 0; j < TOPK; ++j) { s[j] = __expf(s[j] - mx); sum += s[j]; }
    float r = 1.0f / sum;
#pragma unroll
    for (int j = 0; j < TOPK; ++j) attn[(size_t)(b0 + rl) * TOPK + j] = s[j] * r;
  }
}

// ---------------- K6 (fast): 256x256, BK=32 halves, 4-deep, ONE phase per half ------
// Traffic-optimized mapping: mt is XCD-PINNED — XCD x owns mt in [x*8, x*8+8), sweeping
// nt 0..7 per mt. The 1MB A panel is fetched once into the XCD's L2 and re-read 7x from
// L2 (A re-reads leave L3/HBM). B's hot footprint is 8MB -> L3-resident for all XCDs.
// Epilogue uses nontemporal no/out so the 256MB f32 streams don't evict A_sw/B_sw.
union GemmSmem {
  struct { unsigned short A[4][8192]; unsigned short B[4][8192]; } s;  // 128 KB
  float ep[4096];  // 16 KB epilogue alias (after final barrier, all counts drained)
};

#define STAGE_M(SW, RB, LB, h_, b_) do {                                         \
    size_t o0 = (((size_t)((RB) + rh0) * 32 + ((h_) >> 1)) << 10) + (((h_) & 1) << 9); \
    size_t o1 = (((size_t)((RB) + rh1) * 32 + ((h_) >> 1)) << 10) + (((h_) & 1) << 9); \
    gload16((SW) + o0 + lane * 8, (LB)[b_] + rh0 * 512);                         \
    gload16((SW) + o1 + lane * 8, (LB)[b_] + rh1 * 512);                         \
  } while (0)

__global__ __launch_bounds__(512, 1) void k_gemm_bf(
    const unsigned short* __restrict__ A_sw, const unsigned short* __restrict__ B_sw,
    const float* __restrict__ no, const float* __restrict__ bg,
    const float* __restrict__ attn, const float* __restrict__ vb,
    const float* __restrict__ VW, float* __restrict__ out) {
  __shared__ GemmSmem sm;

  int tid = threadIdx.x;
  int lane = tid & 63, wid = tid >> 6;     // 8 waves
  int fr = lane & 15, fg = lane >> 4;
  int wr = wid >> 2, wc = wid & 3;          // 2 (M) x 4 (N)
  int rh0 = wid * 2, rh1 = wid * 2 + 1;     // this wave's staging segments

  int id = blockIdx.x;                      // 512 blocks
  int mt = (id & 7) * 8 + (id >> 6);        // XCD-pinned A row-panel (L2-resident)
  int nt = (id >> 3) & 7;                   // nt swept 0..7 within the XCD
  int brow = mt * 256, bcol = nt * 256;
  int rbA = mt * 16, rbB = nt * 16;

  f32x4 acc[8][4];
#pragma unroll
  for (int m = 0; m < 8; ++m)
#pragma unroll
    for (int n = 0; n < 4; ++n) acc[m][n] = (f32x4){0.f, 0.f, 0.f, 0.f};

  // prologue: stage halves 0,1,2; wait own h0 (oldest 4) landed
  STAGE_M(A_sw, rbA, sm.s.A, 0, 0); STAGE_M(B_sw, rbB, sm.s.B, 0, 0);
  STAGE_M(A_sw, rbA, sm.s.A, 1, 1); STAGE_M(B_sw, rbB, sm.s.B, 1, 1);
  STAGE_M(A_sw, rbA, sm.s.A, 2, 2); STAGE_M(B_sw, rbB, sm.s.B, 2, 2);
  asm volatile("s_waitcnt vmcnt(8)" ::: "memory");
  __builtin_amdgcn_s_barrier();

  s16x8 af[8], bfr[4];
  int rdo = fg * 128 + fr * 8;
  for (int h = 0; h < 64; ++h) {
    int bh = h & 3;
    const unsigned short* Ab = sm.s.A[bh];
    const unsigned short* Bb = sm.s.B[bh];
    const bool st = (h < 61);

#pragma unroll
    for (int m = 0; m < 8; ++m) af[m]  = *(const s16x8*)(Ab + (wr*8 + m) * 512 + rdo);
#pragma unroll
    for (int n = 0; n < 4; ++n) bfr[n] = *(const s16x8*)(Bb + (wc*4 + n) * 512 + rdo);
    if (st) {
      STAGE_M(A_sw, rbA, sm.s.A, h + 3, (h + 3) & 3);
      STAGE_M(B_sw, rbB, sm.s.B, h + 3, (h + 3) & 3);
    }
    __builtin_amdgcn_s_barrier();
    asm volatile("s_waitcnt lgkmcnt(0)" ::: "memory");
    __builtin_amdgcn_sched_barrier(0);
    __builtin_amdgcn_s_setprio(1);
#pragma unroll
    for (int n = 0; n < 4; ++n)
#pragma unroll
      for (int m = 0; m < 8; ++m)
        acc[m][n] = __builtin_amdgcn_mfma_f32_16x16x32_bf16(af[m], bfr[n], acc[m][n], 0, 0, 0);
    __builtin_amdgcn_s_setprio(0);
    if (st) asm volatile("s_waitcnt vmcnt(8)" ::: "memory");  // half h+1 landed
    else    asm volatile("s_waitcnt vmcnt(0)" ::: "memory");  // tail drain
    __builtin_amdgcn_s_barrier();
  }

  // epilogue staging (aliases LDS; after final barrier, all vmcnt drained)
  for (int x = tid; x < 1280; x += 512) sm.ep[x] = attn[(size_t)brow * TOPK + x];
  for (int x = tid; x < 1280; x += 512) { int j = x >> 8, c = x & 255; sm.ep[1280 + x] = VW[j*D + bcol + c]; }
  for (int x = tid; x < 1280; x += 512) { int j = x >> 8, c = x & 255; sm.ep[2560 + x] = vb[j*D + bcol + c]; }
  if (tid < 256) sm.ep[3840 + tid] = bg[bcol + tid];
  __syncthreads();

#pragma unroll
  for (int m = 0; m < 8; ++m) {
    int rbase = wr * 128 + m * 16 + fg * 4;
#pragma unroll
    for (int n = 0; n < 4; ++n) {
      int c = wc * 64 + n * 16 + fr;
      float vw0 = sm.ep[1280 + 0*256 + c], vw1 = sm.ep[1280 + 1*256 + c], vw2 = sm.ep[1280 + 2*256 + c],
            vw3 = sm.ep[1280 + 3*256 + c], vw4 = sm.ep[1280 + 4*256 + c];
      float v0 = sm.ep[2560 + 0*256 + c], v1 = sm.ep[2560 + 1*256 + c], v2 = sm.ep[2560 + 2*256 + c],
            v3 = sm.ep[2560 + 3*256 + c], v4 = sm.ep[2560 + 4*256 + c];
      float bgc = sm.ep[3840 + c];
#pragma unroll
      for (int i = 0; i < 4; ++i) {
        int r = rbase + i;
        float a0 = sm.ep[r*5+0], a1 = sm.ep[r*5+1], a2 = sm.ep[r*5+2], a3 = sm.ep[r*5+3], a4 = sm.ep[r*5+4];
        float gl = acc[m][n][i] + bgc + a0*vw0 + a1*vw1 + a2*vw2 + a3*vw3 + a4*vw4;
        float att = a0*v0 + a1*v1 + a2*v2 + a3*v3 + a4*v4;
        float gate = 1.0f / (1.0f + __expf(-gl));
        size_t gi = (size_t)(brow + r) * D + bcol + c;
        float nv = __builtin_nontemporal_load(&no[gi]);
        __builtin_nontemporal_store(nv + gate * att, &out[gi]);
      }
    }
  }
}

// ---------------- K6 (fallback): f32-staging GEMM ----------------
#define BM 128
#define BN 128
#define BKf 32
#define LDK (BKf + 8)

__global__ __launch_bounds__(256) void k_gemm_f32(
    const float* __restrict__ no, const float* __restrict__ Wg,
    const float* __restrict__ bg, const float* __restrict__ attn,
    const float* __restrict__ vb, const float* __restrict__ VW,
    float* __restrict__ out) {
  __shared__ unsigned short As[BM * LDK];
  __shared__ unsigned short Bs[BN * LDK];
  __shared__ float ep[2048];

  int tid = threadIdx.x;
  int lane = tid & 63, wid = tid >> 6;
  int brow = blockIdx.x * BM;
  int bcol = blockIdx.y * BN;
  int wr = wid >> 1, wc = wid & 1;

  f32x4 acc[4][4];
#pragma unroll
  for (int m = 0; m < 4; ++m)
#pragma unroll
    for (int n = 0; n < 4; ++n) acc[m][n] = (f32x4){0.f, 0.f, 0.f, 0.f};

  int fr = lane & 15, fg = lane >> 4;

  for (int kt = 0; kt < D / BKf; ++kt) {
    int k0 = kt * BKf;
#pragma unroll
    for (int i = 0; i < 4; ++i) {
      int fid = tid + i * 256;
      int row = fid >> 3, c4 = (fid & 7) * 4;
      f32x4 a4 = *(const f32x4*)(no + (size_t)(brow + row) * D + k0 + c4);
      f32x4 b4 = *(const f32x4*)(Wg + (size_t)(bcol + row) * (2 * D) + k0 + c4);
      u16x4 ab, bb;
      ab[0] = f2bf(a4[0]); ab[1] = f2bf(a4[1]); ab[2] = f2bf(a4[2]); ab[3] = f2bf(a4[3]);
      bb[0] = f2bf(b4[0]); bb[1] = f2bf(b4[1]); bb[2] = f2bf(b4[2]); bb[3] = f2bf(b4[3]);
      *(u16x4*)(&As[row * LDK + c4]) = ab;
      *(u16x4*)(&Bs[row * LDK + c4]) = bb;
    }
    __syncthreads();
    s16x8 af[4], bfr[4];
#pragma unroll
    for (int m = 0; m < 4; ++m) af[m] = *(const s16x8*)(&As[(wr*64 + m*16 + fr) * LDK + fg*8]);
#pragma unroll
    for (int n = 0; n < 4; ++n) bfr[n] = *(const s16x8*)(&Bs[(wc*64 + n*16 + fr) * LDK + fg*8]);
#pragma unroll
    for (int m = 0; m < 4; ++m)
#pragma unroll
      for (int n = 0; n < 4; ++n)
        acc[m][n] = __builtin_amdgcn_mfma_f32_16x16x32_bf16(af[m], bfr[n], acc[m][n], 0, 0, 0);
    __syncthreads();
  }

  for (int x = tid; x < 640; x += 256) ep[x] = attn[(size_t)brow * TOPK + x];
  for (int x = tid; x < 640; x += 256) { int j = x >> 7, c = x & 127; ep[640 + x]  = VW[j*D + bcol + c]; }
  for (int x = tid; x < 640; x += 256) { int j = x >> 7, c = x & 127; ep[1280 + x] = vb[j*D + bcol + c]; }
  if (tid < 128) ep[1920 + tid] = bg[bcol + tid];
  __syncthreads();

#pragma unroll
  for (int m = 0; m < 4; ++m) {
    int rbase = wr * 64 + m * 16 + fg * 4;
#pragma unroll
    for (int n = 0; n < 4; ++n) {
      int c = wc * 64 + n * 16 + fr;
      float vw0 = ep[640 + 0*128 + c], vw1 = ep[640 + 1*128 + c], vw2 = ep[640 + 2*128 + c],
            vw3 = ep[640 + 3*128 + c], vw4 = ep[640 + 4*128 + c];
      float v0 = ep[1280 + 0*128 + c], v1 = ep[1280 + 1*128 + c], v2 = ep[1280 + 2*128 + c],
            v3 = ep[1280 + 3*128 + c], v4 = ep[1280 + 4*128 + c];
      float bgc = ep[1920 + c];
#pragma unroll
      for (int i = 0; i < 4; ++i) {
        int r = rbase + i;
        float a0 = ep[r*5+0], a1 = ep[r*5+1], a2 = ep[r*5+2], a3 = ep[r*5+3], a4 = ep[r*5+4];
        float gl = acc[m][n][i] + bgc + a0*vw0 + a1*vw1 + a2*vw2 + a3*vw3 + a4*vw4;
        float att = a0*v0 + a1*v1 + a2*v2 + a3*v3 + a4*v4;
        float gate = 1.0f / (1.0f + __expf(-gl));
        size_t gi = (size_t)(brow + r) * D + bcol + c;
        out[gi] = no[gi] + gate * att;
      }
    }
  }
}

extern "C" void kernel_launch(void* const* d_in, const int* in_sizes, int n_in,
                              void* d_out, int out_size, void* d_ws, size_t ws_size,
                              hipStream_t stream) {
  (void)in_sizes; (void)n_in; (void)out_size;
  const float* no    = (const float*)d_in[0];
  const float* ce    = (const float*)d_in[1];
  const float* bank  = (const float*)d_in[2];
  const float* mvals = (const float*)d_in[3];
  const float* Wq    = (const float*)d_in[4];
  const float* bq    = (const float*)d_in[5];
  const float* Wk    = (const float*)d_in[6];
  const float* bk    = (const float*)d_in[7];
  const float* Wv    = (const float*)d_in[8];
  const float* bvp   = (const float*)d_in[9];
  const float* Wg    = (const float*)d_in[10];
  const float* bg    = (const float*)d_in[11];
  float* out = (float*)d_out;

  char* ws = (char*)d_ws;
  float* sims     = (float*)(ws + 16384);
  float* top_sims = (float*)(ws + 220160);
  int*   top_idx  = (int*)  (ws + 220192);
  float* sbias    = (float*)(ws + 220224);
  float* kb       = (float*)(ws + 221184);
  float* vb       = (float*)(ws + 262144);
  float* VW       = (float*)(ws + 303104);
  float* KQpart   = (float*)(ws + 344064);
  float* KQ       = (float*)(ws + 1654784);
  float* attn     = (float*)(ws + 1695744);
  unsigned short* A_sw = (unsigned short*)(ws + 4194304);
  unsigned short* B_sw = (unsigned short*)(ws + 4194304 + (size_t)B_ROWS * D * 2);

  const size_t ws_need = 4194304 + (size_t)B_ROWS * D * 2 + (size_t)D * D * 2;
  const bool fast = ws_size >= ws_need;

  k_sims<<<1024, 256, 0, stream>>>(bank, ce, sims);
  k_topk<<<1, 256, 0, stream>>>(sims, top_sims, top_idx);
  k_kv<<<512, 256, 0, stream>>>(mvals, top_idx, Wk, bk, Wv, bvp, kb, vb);
  k_prep<<<fast ? 801 : 769, 256, 0, stream>>>(Wq, bq, Wg, kb, vb, KQpart, VW, sbias, B_sw);
  k_red<<<40, 256, 0, stream>>>(KQpart, KQ);
  if (fast) {
    k_attn<true><<<256, 256, 0, stream>>>(no, KQ, sbias, top_sims, attn, A_sw);
    k_gemm_bf<<<512, 512, 0, stream>>>(A_sw, B_sw, no, bg, attn, vb, VW, out);
  } else {
    k_attn<false><<<256, 256, 0, stream>>>(no, KQ, sbias, top_sims, attn, A_sw);
    k_gemm_f32<<<dim3(B_ROWS / BM, D / BN), 256, 0, stream>>>(no, Wg, bg, attn, vb, VW, out);
  }
}